// Round 5
// baseline (922.536 us; speedup 1.0000x reference)
//
#include <hip/hip_runtime.h>
#include <hip/hip_bf16.h>

#define NP     100000   // n_paths
#define PLEN   5        // path length
#define NLINKS 10000    // n_links
#define DIM    32       // state dim
#define TITERS 8        // message passing iterations
#define E_TOT  (NP * PLEN)

using bf16x8 = __attribute__((ext_vector_type(8))) short;
using f32x4  = __attribute__((ext_vector_type(4))) float;
union FragCast { uint4 u; bf16x8 v; };

// ---------- helpers ----------
__device__ __forceinline__ float fast_sigmoid(float v) {
    return 1.0f / (1.0f + __expf(-v));
}
__device__ __forceinline__ float fast_tanh(float v) {
    float e = __expf(-2.0f * fabsf(v));
    float t = (1.0f - e) / (1.0f + e);
    return v >= 0.0f ? t : -t;
}
__device__ __forceinline__ float seluf(float v) {
    const float sc = 1.0507009873554805f;
    const float al = 1.6732632423543772f;
    return v > 0.0f ? sc * v : sc * al * (__expf(v) - 1.0f);
}
__device__ __forceinline__ unsigned short f2bf(float f) {
    union { float f; unsigned u; } c; c.f = f;
    unsigned u = c.u;
    return (unsigned short)((u + 0x7fffu + ((u >> 16) & 1u)) >> 16);
}
__device__ __forceinline__ float bf2f(unsigned short b) {
    union { unsigned u; float f; } c; c.u = ((unsigned)b) << 16;
    return c.f;
}
__device__ __forceinline__ void split_bf16(const float (&v)[8], bf16x8& hi, bf16x8& lo) {
    unsigned uh[4], ul[4];
    #pragma unroll
    for (int i = 0; i < 4; ++i) {
        unsigned short h0 = f2bf(v[2*i]),   h1 = f2bf(v[2*i+1]);
        float r0 = v[2*i] - bf2f(h0),       r1 = v[2*i+1] - bf2f(h1);
        unsigned short l0 = f2bf(r0),       l1 = f2bf(r1);
        uh[i] = (unsigned)h0 | ((unsigned)h1 << 16);
        ul[i] = (unsigned)l0 | ((unsigned)l1 << 16);
    }
    FragCast ch, cl;
    ch.u.x = uh[0]; ch.u.y = uh[1]; ch.u.z = uh[2]; ch.u.w = uh[3];
    cl.u.x = ul[0]; cl.u.y = ul[1]; cl.u.z = ul[2]; cl.u.w = ul[3];
    hi = ch.v; lo = cl.v;
}

// C'-layout (per-lane: hC[hf][rg] = h[path=l15][dim=hf*16+quad*4+rg]) to
// B-layout (b8[j] = h[path=l15][dim = chunk(quad)*8 + j], chunk={0,2,1,3})
// via one xor-16 lane exchange. No LDS, no barriers.
__device__ __forceinline__ void cprime_to_b(const float (&hC)[2][4], int quad,
                                            float (&b8)[8])
{
    const bool even = (quad & 1) == 0;
    #pragma unroll
    for (int rg = 0; rg < 4; ++rg) {
        float send = even ? hC[1][rg] : hC[0][rg];
        float recv = __shfl_xor(send, 16);
        b8[rg]     = even ? hC[0][rg] : recv;
        b8[4 + rg] = even ? recv      : hC[1][rg];
    }
}

// ---------- init + CSR count + iteration-0 xg ----------
// xg layout: [link][32][4] = {z, r, n, pad} per state-col, biases folded in.
__global__ __launch_bounds__(256) void init_kernel(
    const int*   __restrict__ links,
    const float* __restrict__ cap, const float* __restrict__ pol, const float* __restrict__ wts,
    const float* __restrict__ bw,  const float* __restrict__ tos,
    const float* __restrict__ pk,  const float* __restrict__ avg,
    const float* __restrict__ Wp,  const float* __restrict__ bp,
    float* __restrict__ link_state, float* __restrict__ path_state,
    float* __restrict__ xg,
    int* __restrict__ cnt)
{
    int i = blockIdx.x * 256 + threadIdx.x;
    if (i < E_TOT) atomicAdd(&cnt[links[i]], 1);
    if (i < NLINKS) {
        float row[DIM];
        #pragma unroll
        for (int c = 0; c < DIM; ++c) row[c] = 0.0f;
        row[0] = cap[i]; row[1] = pol[i]; row[2] = wts[i];
        float4* o = (float4*)(link_state + (size_t)i * DIM);
        #pragma unroll
        for (int c = 0; c < 8; ++c) {
            float4 v = { row[4*c], row[4*c+1], row[4*c+2], row[4*c+3] };
            o[c] = v;
        }
        // xg0 = ls0 @ Wp + folded biases; ls0 has only dims 0..2 nonzero.
        float a = row[0], b = row[1], c3 = row[2];
        float4* xo = (float4*)(xg + (size_t)i * 128);
        #pragma unroll 4
        for (int c = 0; c < 32; ++c) {
            float z = a * Wp[c]      + b * Wp[96+c]  + c3 * Wp[192+c] + bp[c]    + bp[96+c];
            float r = a * Wp[32+c]   + b * Wp[128+c] + c3 * Wp[224+c] + bp[32+c] + bp[128+c];
            float n = a * Wp[64+c]   + b * Wp[160+c] + c3 * Wp[256+c] + bp[64+c];
            float4 v = { z, r, n, 0.0f };
            xo[c] = v;
        }
    }
    if (i < NP) {
        float row[DIM];
        #pragma unroll
        for (int c = 0; c < DIM; ++c) row[c] = 0.0f;
        row[0] = bw[i]; row[1] = tos[i]; row[2] = pk[i]; row[3] = avg[i];
        float4* o = (float4*)(path_state + (size_t)i * DIM);
        #pragma unroll
        for (int c = 0; c < 8; ++c) {
            float4 v = { row[4*c], row[4*c+1], row[4*c+2], row[4*c+3] };
            o[c] = v;
        }
    }
}

// ---------- prep item helpers ----------
// PERM_U: U-parts get the k-chunk permutation {0,2,1,3} (swapped-operand path
// GRU consumes them as the MFMA A operand against shfl-exchanged h); W-parts
// stay natural (aglk consumes them against naturally-ordered h).
template <bool PERM_U>
__device__ __forceinline__ void wprep_item(const float* __restrict__ W,
                                           const float* __restrict__ U,
                                           unsigned short* __restrict__ ofr, int idx)
{
    int j = idx & 7, lane = (idx >> 3) & 63, g = idx >> 9;
    int q = lane >> 4;
    int kN = q * 8 + j;
    int kP = PERM_U ? ((((q & 1) << 1) | (q >> 1)) * 8 + j) : kN;
    int n = g * 16 + (lane & 15);
    float w = W[kN * 96 + n];
    float u = U[kP * 96 + n];
    unsigned short whi = f2bf(w); unsigned short wlo = f2bf(w - bf2f(whi));
    unsigned short uhi = f2bf(u); unsigned short ulo = f2bf(u - bf2f(uhi));
    ofr[0 * 3072 + idx] = whi;
    ofr[1 * 3072 + idx] = wlo;
    ofr[2 * 3072 + idx] = uhi;
    ofr[3 * 3072 + idx] = ulo;
}

__device__ __forceinline__ void rprep_item(const float* __restrict__ R1,
                                           const float* __restrict__ R2,
                                           unsigned short* __restrict__ rfr, int idx)
{
    if (idx < 8192) {
        // R1 fragments: k-chunk permuted to match swapped-GRU h0 output layout
        int j = idx & 7, lane = (idx >> 3) & 63, g = idx >> 9;
        int q = lane >> 4;
        int k = (((q & 1) << 1) | (q >> 1)) * 8 + j;
        int n = g * 16 + (lane & 15);
        float v = R1[k * 256 + n];
        unsigned short hi = f2bf(v);
        rfr[idx] = hi;
        rfr[8192 + idx] = f2bf(v - bf2f(hi));
    } else {
        int idx2 = idx - 8192;
        int j = idx2 & 7, lane = (idx2 >> 3) & 63, tile = idx2 >> 9;
        int c = tile >> 4, g = tile & 15;
        int k = c * 32 + (lane >> 4) * 8 + j;
        int n = g * 16 + (lane & 15);
        float v = R2[k * 256 + n];
        unsigned short hi = f2bf(v);
        rfr[16384 + idx2] = hi;
        rfr[16384 + 65536 + idx2] = f2bf(v - bf2f(hi));
    }
}

// ---------- merged prep: block 0 = CSR scan; blocks 1.. = weight frag prep ----
__global__ __launch_bounds__(256) void prep_kernel(
    const int*   __restrict__ cnt,
    int* __restrict__ row_start, int* __restrict__ cursor,
    const float* __restrict__ Wp, const float* __restrict__ Up,
    unsigned short* __restrict__ wfr,
    const float* __restrict__ Wl, const float* __restrict__ Ul,
    unsigned short* __restrict__ lfr,
    const float* __restrict__ R1, const float* __restrict__ R2,
    unsigned short* __restrict__ rfr)
{
    int t = threadIdx.x;
    if (blockIdx.x == 0) {
        __shared__ int s[256];
        const int CH = (NLINKS + 255) / 256;   // 40
        int base = t * CH;
        int sum = 0;
        for (int i = 0; i < CH; ++i) {
            int idx = base + i;
            if (idx < NLINKS) sum += cnt[idx];
        }
        s[t] = sum;
        __syncthreads();
        for (int off = 1; off < 256; off <<= 1) {
            int v = (t >= off) ? s[t - off] : 0;
            __syncthreads();
            s[t] += v;
            __syncthreads();
        }
        int run = s[t] - sum;
        for (int i = 0; i < CH; ++i) {
            int idx = base + i;
            if (idx < NLINKS) {
                row_start[idx] = run;
                cursor[idx]    = run;
                run += cnt[idx];
            }
        }
        if (t == 255) row_start[NLINKS] = s[255];
        return;
    }
    int idx = (blockIdx.x - 1) * 256 + t;
    if (idx < 3072) {
        wprep_item<true>(Wp, Up, wfr, idx);     // path GRU: U permuted
    } else if (idx < 6144) {
        wprep_item<false>(Wl, Ul, lfr, idx - 3072);  // link GRU: natural
    } else if (idx < 6144 + 8192 + 65536) {
        rprep_item(R1, R2, rfr, idx - 6144);
    }
}

__global__ __launch_bounds__(256) void csr_scatter(const int* __restrict__ links,
                                                   int* __restrict__ cursor,
                                                   int* __restrict__ slot)
{
    int e = blockIdx.x * 256 + threadIdx.x;
    if (e < E_TOT) slot[e] = atomicAdd(&cursor[links[e]], 1);
}

// ---------- shared device body: 5-hop swapped-operand MFMA path GRU ----------
// C' = mfma(U^T_frag, h_B) puts paths in C' columns (lane = own path), dims in
// rows. Per-hop layout fix is one xor-16 register exchange (cprime_to_b) —
// no LDS, no lgkmcnt barriers in the hop loop. b8 output dims are in permuted
// chunk order {0,2,1,3}, matched by the prep-time k permutation of U/R1 frags.
template <bool STORE_M>
__device__ __forceinline__ void path_gru_body(
    int p0, int l15, int quad,
    const int* __restrict__ links,
    const float* __restrict__ xg,
    const unsigned short* __restrict__ wfr,
    const float* __restrict__ bp,
    const int* __restrict__ slot,
    const float* __restrict__ path_state,
    float* __restrict__ m,
    float (&hB)[8])
{
    int lane = quad * 16 + l15;
    int p = p0 + l15;
    int kc = ((quad & 1) << 1) | (quad >> 1);   // natural chunk held post-exchange

    int plk[PLEN];
    #pragma unroll
    for (int l = 0; l < PLEN; ++l) plk[l] = links[p * PLEN + l];
    int sl[PLEN];
    if (STORE_M) {
        #pragma unroll
        for (int l = 0; l < PLEN; ++l) sl[l] = slot[p * PLEN + l];
    }

    // U fragments (A operand; hi/lo), k-permuted at prep time
    bf16x8 Uh[6], Ul[6];
    {
        const uint4* base = (const uint4*)wfr;
        #pragma unroll
        for (int g = 0; g < 6; ++g) {
            FragCast a;
            a.u = base[2 * 384 + g * 64 + lane]; Uh[g] = a.v;
            a.u = base[3 * 384 + g * 64 + lane]; Ul[g] = a.v;
        }
    }
    // recurrent n-gate bias per (hf, rg): dim = hf*16 + quad*4 + rg
    float bnh[2][4];
    {
        float4 b0 = *(const float4*)(bp + 96 + 64 + quad * 4);
        float4 b1 = *(const float4*)(bp + 96 + 64 + 16 + quad * 4);
        bnh[0][0]=b0.x; bnh[0][1]=b0.y; bnh[0][2]=b0.z; bnh[0][3]=b0.w;
        bnh[1][0]=b1.x; bnh[1][1]=b1.y; bnh[1][2]=b1.z; bnh[1][3]=b1.w;
    }

    // h in C'-layout: hC[hf][rg] = h[path=l15][dim=hf*16+quad*4+rg]
    float hC[2][4];
    {
        const float4* ps = (const float4*)(path_state + (size_t)p * DIM);
        float4 c0 = ps[quad], c1 = ps[4 + quad];
        hC[0][0]=c0.x; hC[0][1]=c0.y; hC[0][2]=c0.z; hC[0][3]=c0.w;
        hC[1][0]=c1.x; hC[1][1]=c1.y; hC[1][2]=c1.z; hC[1][3]=c1.w;
    }
    float b8[8];
    cprime_to_b(hC, quad, b8);
    bf16x8 bh, bl;
    split_bf16(b8, bh, bl);

    #pragma unroll
    for (int l = 0; l < PLEN; ++l) {
        // gather own link's precomputed gate pre-activations {z,r,n}
        const float4* xp = (const float4*)(xg + (size_t)plk[l] * 128);
        float4 xv[2][4];
        #pragma unroll
        for (int rg = 0; rg < 4; ++rg) {
            xv[0][rg] = xp[quad * 4 + rg];
            xv[1][rg] = xp[16 + quad * 4 + rg];
        }
        #pragma unroll
        for (int hf = 0; hf < 2; ++hf) {
            f32x4 az  = { xv[hf][0].x, xv[hf][1].x, xv[hf][2].x, xv[hf][3].x };
            f32x4 ar  = { xv[hf][0].y, xv[hf][1].y, xv[hf][2].y, xv[hf][3].y };
            f32x4 ahg = { 0.f, 0.f, 0.f, 0.f };
            int gz = hf, gr = 2 + hf, gn = 4 + hf;
            az  = __builtin_amdgcn_mfma_f32_16x16x32_bf16(Uh[gz], bh, az,  0, 0, 0);
            ar  = __builtin_amdgcn_mfma_f32_16x16x32_bf16(Uh[gr], bh, ar,  0, 0, 0);
            ahg = __builtin_amdgcn_mfma_f32_16x16x32_bf16(Uh[gn], bh, ahg, 0, 0, 0);
            az  = __builtin_amdgcn_mfma_f32_16x16x32_bf16(Ul[gz], bh, az,  0, 0, 0);
            ar  = __builtin_amdgcn_mfma_f32_16x16x32_bf16(Ul[gr], bh, ar,  0, 0, 0);
            ahg = __builtin_amdgcn_mfma_f32_16x16x32_bf16(Ul[gn], bh, ahg, 0, 0, 0);
            az  = __builtin_amdgcn_mfma_f32_16x16x32_bf16(Uh[gz], bl, az,  0, 0, 0);
            ar  = __builtin_amdgcn_mfma_f32_16x16x32_bf16(Uh[gr], bl, ar,  0, 0, 0);
            ahg = __builtin_amdgcn_mfma_f32_16x16x32_bf16(Uh[gn], bl, ahg, 0, 0, 0);
            #pragma unroll
            for (int rg = 0; rg < 4; ++rg) {
                float z  = fast_sigmoid(az[rg]);
                float r  = fast_sigmoid(ar[rg]);
                float hn = fast_tanh(xv[hf][rg].z + r * (ahg[rg] + bnh[hf][rg]));
                hC[hf][rg] = z * hC[hf][rg] + (1.0f - z) * hn;
            }
        }
        cprime_to_b(hC, quad, b8);
        if (STORE_M) {
            float4* dst = (float4*)(m + (size_t)sl[l] * DIM + kc * 8);
            float4 v0 = { b8[0], b8[1], b8[2], b8[3] };
            float4 v1 = { b8[4], b8[5], b8[6], b8[7] };
            dst[0] = v0; dst[1] = v1;
        }
        if (l < PLEN - 1) split_bf16(b8, bh, bl);
    }
    #pragma unroll
    for (int j = 0; j < 8; ++j) hB[j] = b8[j];
}

// ---------- MFMA path GRU kernel (iterations 0..6) — zero LDS ----------
__global__ __launch_bounds__(256) void path_kernel(
    const int*   __restrict__ links,
    const float* __restrict__ xg,
    const unsigned short* __restrict__ wfr,
    const float* __restrict__ bp,
    const int*   __restrict__ slot,
    float* __restrict__ path_state,
    float* __restrict__ m)
{
    int t = threadIdx.x;
    int wave = t >> 6, lane = t & 63;
    int l15 = lane & 15, quad = lane >> 4;
    int p0 = (blockIdx.x * 4 + wave) * 16;
    if (p0 >= NP) return;
    int p = p0 + l15;
    int kc = ((quad & 1) << 1) | (quad >> 1);
    float hB[8];
    path_gru_body<true>(p0, l15, quad, links, xg, wfr, bp,
                        slot, path_state, m, hB);
    float4* ho = (float4*)(path_state + (size_t)p * DIM + kc * 8);
    float4 v0 = { hB[0], hB[1], hB[2], hB[3] };
    float4 v1 = { hB[4], hB[5], hB[6], hB[7] };
    ho[0] = v0; ho[1] = v1;
}

// ---------- segment-sum: one wave per link, coalesced CSR-ordered read ----
__global__ __launch_bounds__(256) void agg_kernel(
    const int* __restrict__ row_start,
    const float* __restrict__ m,
    float* __restrict__ x_sum)
{
    int t = threadIdx.x;
    int wave = t >> 6, lane = t & 63;
    int link = blockIdx.x * 4 + wave;
    if (link >= NLINKS) return;
    int r = lane >> 3;
    int c = lane & 7;
    int s0 = row_start[link], s1 = row_start[link + 1];
    float4 acc = {0.f, 0.f, 0.f, 0.f};
    for (int i = s0 + r; i < s1; i += 8) {
        const float4 v = *(const float4*)(m + (size_t)i * DIM + c * 4);
        acc.x += v.x; acc.y += v.y; acc.z += v.z; acc.w += v.w;
    }
    #pragma unroll
    for (int off = 8; off < 64; off <<= 1) {
        acc.x += __shfl_xor(acc.x, off);
        acc.y += __shfl_xor(acc.y, off);
        acc.z += __shfl_xor(acc.z, off);
        acc.w += __shfl_xor(acc.w, off);
    }
    if (r == 0)
        *(float4*)(x_sum + (size_t)link * DIM + c * 4) = acc;
}

// ---------- link GRU: dense x_sum read, link_state update, next xg ----------
__global__ __launch_bounds__(256) void aglk_kernel(
    const float* __restrict__ x_sum,
    const unsigned short* __restrict__ lfr,
    const float* __restrict__ bl,
    const unsigned short* __restrict__ wfr,
    const float* __restrict__ bp,
    float* __restrict__ link_state,
    float* __restrict__ xg)
{
    __shared__ __align__(16) float T4[4][16 * 36];
    int t = threadIdx.x;
    int wave = t >> 6, lane = t & 63;
    int l15 = lane & 15, quad = lane >> 4;
    int lb = (blockIdx.x * 4 + wave) * 16;
    if (lb >= NLINKS) return;
    float* T = T4[wave];
    int link = lb + l15;

    bf16x8 Wh[6], Wlo[6], Uh[6], Ulo[6];
    {
        const uint4* base = (const uint4*)lfr;
        #pragma unroll
        for (int g = 0; g < 6; ++g) {
            FragCast a;
            a.u = base[0 * 384 + g * 64 + lane]; Wh[g]  = a.v;
            a.u = base[1 * 384 + g * 64 + lane]; Wlo[g] = a.v;
            a.u = base[2 * 384 + g * 64 + lane]; Uh[g]  = a.v;
            a.u = base[3 * 384 + g * 64 + lane]; Ulo[g] = a.v;
        }
    }
    float bz[2], br[2], bnx[2], bnh[2];
    #pragma unroll
    for (int hf = 0; hf < 2; ++hf) {
        int c = hf * 16 + l15;
        bz[hf]  = bl[c]      + bl[96 + c];
        br[hf]  = bl[32 + c] + bl[96 + 32 + c];
        bnx[hf] = bl[64 + c];
        bnh[hf] = bl[96 + 64 + c];
    }

    float x8[8];
    {
        const float4* xs = (const float4*)(x_sum + (size_t)link * DIM + quad * 8);
        float4 a = xs[0], b = xs[1];
        x8[0]=a.x; x8[1]=a.y; x8[2]=a.z; x8[3]=a.w;
        x8[4]=b.x; x8[5]=b.y; x8[6]=b.z; x8[7]=b.w;
    }
    bf16x8 xh, xl;
    split_bf16(x8, xh, xl);

    float hA[8];
    {
        const float4* src = (const float4*)(link_state + (size_t)link * DIM + quad * 8);
        float4 v0 = src[0], v1 = src[1];
        hA[0]=v0.x; hA[1]=v0.y; hA[2]=v0.z; hA[3]=v0.w;
        hA[4]=v1.x; hA[5]=v1.y; hA[6]=v1.z; hA[7]=v1.w;
    }
    #pragma unroll
    for (int j = 0; j < 8; ++j) T[l15 * 36 + quad * 8 + j] = hA[j];
    __asm__ volatile("s_waitcnt lgkmcnt(0)" ::: "memory");
    float hC[2][4];
    #pragma unroll
    for (int hf = 0; hf < 2; ++hf)
        #pragma unroll
        for (int rg = 0; rg < 4; ++rg)
            hC[hf][rg] = T[(quad * 4 + rg) * 36 + hf * 16 + l15];
    bf16x8 ah, al;
    split_bf16(hA, ah, al);

    #pragma unroll
    for (int hf = 0; hf < 2; ++hf) {
        f32x4 az = {0.f,0.f,0.f,0.f}, ar = {0.f,0.f,0.f,0.f};
        f32x4 axn = {0.f,0.f,0.f,0.f}, ahg = {0.f,0.f,0.f,0.f};
        int gz = hf, gr = 2 + hf, gn = 4 + hf;
        az = __builtin_amdgcn_mfma_f32_16x16x32_bf16(xh, Wh[gz],  az, 0, 0, 0);
        az = __builtin_amdgcn_mfma_f32_16x16x32_bf16(xh, Wlo[gz], az, 0, 0, 0);
        az = __builtin_amdgcn_mfma_f32_16x16x32_bf16(xl, Wh[gz],  az, 0, 0, 0);
        az = __builtin_amdgcn_mfma_f32_16x16x32_bf16(ah, Uh[gz],  az, 0, 0, 0);
        az = __builtin_amdgcn_mfma_f32_16x16x32_bf16(ah, Ulo[gz], az, 0, 0, 0);
        az = __builtin_amdgcn_mfma_f32_16x16x32_bf16(al, Uh[gz],  az, 0, 0, 0);
        ar = __builtin_amdgcn_mfma_f32_16x16x32_bf16(xh, Wh[gr],  ar, 0, 0, 0);
        ar = __builtin_amdgcn_mfma_f32_16x16x32_bf16(xh, Wlo[gr], ar, 0, 0, 0);
        ar = __builtin_amdgcn_mfma_f32_16x16x32_bf16(xl, Wh[gr],  ar, 0, 0, 0);
        ar = __builtin_amdgcn_mfma_f32_16x16x32_bf16(ah, Uh[gr],  ar, 0, 0, 0);
        ar = __builtin_amdgcn_mfma_f32_16x16x32_bf16(ah, Ulo[gr], ar, 0, 0, 0);
        ar = __builtin_amdgcn_mfma_f32_16x16x32_bf16(al, Uh[gr],  ar, 0, 0, 0);
        axn = __builtin_amdgcn_mfma_f32_16x16x32_bf16(xh, Wh[gn],  axn, 0, 0, 0);
        axn = __builtin_amdgcn_mfma_f32_16x16x32_bf16(xh, Wlo[gn], axn, 0, 0, 0);
        axn = __builtin_amdgcn_mfma_f32_16x16x32_bf16(xl, Wh[gn],  axn, 0, 0, 0);
        ahg = __builtin_amdgcn_mfma_f32_16x16x32_bf16(ah, Uh[gn],  ahg, 0, 0, 0);
        ahg = __builtin_amdgcn_mfma_f32_16x16x32_bf16(ah, Ulo[gn], ahg, 0, 0, 0);
        ahg = __builtin_amdgcn_mfma_f32_16x16x32_bf16(al, Uh[gn],  ahg, 0, 0, 0);
        #pragma unroll
        for (int rg = 0; rg < 4; ++rg) {
            float z  = fast_sigmoid(az[rg] + bz[hf]);
            float r  = fast_sigmoid(ar[rg] + br[hf]);
            float hn = fast_tanh(axn[rg] + bnx[hf] + r * (ahg[rg] + bnh[hf]));
            hC[hf][rg] = z * hC[hf][rg] + (1.0f - z) * hn;
        }
    }

    __asm__ volatile("s_waitcnt lgkmcnt(0)" ::: "memory");
    #pragma unroll
    for (int hf = 0; hf < 2; ++hf)
        #pragma unroll
        for (int rg = 0; rg < 4; ++rg)
            T[(quad * 4 + rg) * 36 + hf * 16 + l15] = hC[hf][rg];
    __asm__ volatile("s_waitcnt lgkmcnt(0)" ::: "memory");
    {
        const float4* rd = (const float4*)(T + l15 * 36 + quad * 8);
        float4 v0 = rd[0], v1 = rd[1];
        hA[0]=v0.x; hA[1]=v0.y; hA[2]=v0.z; hA[3]=v0.w;
        hA[4]=v1.x; hA[5]=v1.y; hA[6]=v1.z; hA[7]=v1.w;
    }
    float4* ho = (float4*)(link_state + (size_t)link * DIM + quad * 8);
    float4 v0 = { hA[0], hA[1], hA[2], hA[3] };
    float4 v1 = { hA[4], hA[5], hA[6], hA[7] };
    ho[0] = v0; ho[1] = v1;

    // ---- xg for next path iteration: new_h @ Wp + folded path biases ----
    bf16x8 nh, nl;
    split_bf16(hA, nh, nl);
    {
        const uint4* wb = (const uint4*)wfr;
        #pragma unroll
        for (int hf2 = 0; hf2 < 2; ++hf2) {
            int c0 = hf2 * 16 + l15;
            float foldz = bp[c0]      + bp[96 + c0];
            float foldr = bp[32 + c0] + bp[128 + c0];
            float foldn = bp[64 + c0];
            FragCast wzh, wzl, wrh, wrl, wnh, wnl;
            wzh.u = wb[0 * 384 + (hf2)     * 64 + lane];
            wzl.u = wb[1 * 384 + (hf2)     * 64 + lane];
            wrh.u = wb[0 * 384 + (2 + hf2) * 64 + lane];
            wrl.u = wb[1 * 384 + (2 + hf2) * 64 + lane];
            wnh.u = wb[0 * 384 + (4 + hf2) * 64 + lane];
            wnl.u = wb[1 * 384 + (4 + hf2) * 64 + lane];
            f32x4 cz = {0.f,0.f,0.f,0.f}, cr = {0.f,0.f,0.f,0.f}, cn = {0.f,0.f,0.f,0.f};
            cz = __builtin_amdgcn_mfma_f32_16x16x32_bf16(nh, wzh.v, cz, 0, 0, 0);
            cr = __builtin_amdgcn_mfma_f32_16x16x32_bf16(nh, wrh.v, cr, 0, 0, 0);
            cn = __builtin_amdgcn_mfma_f32_16x16x32_bf16(nh, wnh.v, cn, 0, 0, 0);
            cz = __builtin_amdgcn_mfma_f32_16x16x32_bf16(nh, wzl.v, cz, 0, 0, 0);
            cr = __builtin_amdgcn_mfma_f32_16x16x32_bf16(nh, wrl.v, cr, 0, 0, 0);
            cn = __builtin_amdgcn_mfma_f32_16x16x32_bf16(nh, wnl.v, cn, 0, 0, 0);
            cz = __builtin_amdgcn_mfma_f32_16x16x32_bf16(nl, wzh.v, cz, 0, 0, 0);
            cr = __builtin_amdgcn_mfma_f32_16x16x32_bf16(nl, wrh.v, cr, 0, 0, 0);
            cn = __builtin_amdgcn_mfma_f32_16x16x32_bf16(nl, wnh.v, cn, 0, 0, 0);
            #pragma unroll
            for (int rg = 0; rg < 4; ++rg) {
                float4 v = { cz[rg] + foldz, cr[rg] + foldr, cn[rg] + foldn, 0.f };
                *(float4*)(xg + (size_t)(lb + quad * 4 + rg) * 128 + c0 * 4) = v;
            }
        }
    }
}

// ---------- fused: final path GRU iteration + MFMA readout ----------
__global__ __launch_bounds__(128, 1) void readout_kernel(
    const int*   __restrict__ links,
    const float* __restrict__ xg,
    const unsigned short* __restrict__ wfr,
    const float* __restrict__ bp,
    const float* __restrict__ path_state,
    const unsigned short* __restrict__ rfr,
    const float* __restrict__ Rb1, const float* __restrict__ Rb2,
    const float* __restrict__ R3,  const float* __restrict__ Rb3,
    float* __restrict__ out)
{
    __shared__ __align__(16) float T2[2][16 * 260];
    int t = threadIdx.x;
    int wave = t >> 6, lane = t & 63;
    int l15 = lane & 15, quad = lane >> 4;
    int p0 = (blockIdx.x * 2 + wave) * 16;
    if (p0 >= NP) return;
    float* T = T2[wave];

    float h0[8];
    path_gru_body<false>(p0, l15, quad, links, xg, wfr, bp,
                         nullptr, path_state, nullptr, h0);

    const uint4* r1h = (const uint4*)rfr;
    const uint4* r1l = r1h + 1024;
    const uint4* r2h = r1l + 1024;
    const uint4* r2l = r2h + 8192;

    bf16x8 a0h, a0l;
    split_bf16(h0, a0h, a0l);
    // R1: 4 concurrent accumulator chains per pass (16 outputs of 256)
    #pragma unroll 1
    for (int g = 0; g < 16; g += 4) {
        f32x4 c0 = {0.f,0.f,0.f,0.f}, c1 = {0.f,0.f,0.f,0.f};
        f32x4 c2 = {0.f,0.f,0.f,0.f}, c3 = {0.f,0.f,0.f,0.f};
        FragCast b0h, b0l, b1h, b1l, b2h, b2l, b3h, b3l;
        b0h.u = r1h[(g+0) * 64 + lane]; b0l.u = r1l[(g+0) * 64 + lane];
        b1h.u = r1h[(g+1) * 64 + lane]; b1l.u = r1l[(g+1) * 64 + lane];
        b2h.u = r1h[(g+2) * 64 + lane]; b2l.u = r1l[(g+2) * 64 + lane];
        b3h.u = r1h[(g+3) * 64 + lane]; b3l.u = r1l[(g+3) * 64 + lane];
        c0 = __builtin_amdgcn_mfma_f32_16x16x32_bf16(a0h, b0h.v, c0, 0, 0, 0);
        c1 = __builtin_amdgcn_mfma_f32_16x16x32_bf16(a0h, b1h.v, c1, 0, 0, 0);
        c2 = __builtin_amdgcn_mfma_f32_16x16x32_bf16(a0h, b2h.v, c2, 0, 0, 0);
        c3 = __builtin_amdgcn_mfma_f32_16x16x32_bf16(a0h, b3h.v, c3, 0, 0, 0);
        c0 = __builtin_amdgcn_mfma_f32_16x16x32_bf16(a0h, b0l.v, c0, 0, 0, 0);
        c1 = __builtin_amdgcn_mfma_f32_16x16x32_bf16(a0h, b1l.v, c1, 0, 0, 0);
        c2 = __builtin_amdgcn_mfma_f32_16x16x32_bf16(a0h, b2l.v, c2, 0, 0, 0);
        c3 = __builtin_amdgcn_mfma_f32_16x16x32_bf16(a0h, b3l.v, c3, 0, 0, 0);
        c0 = __builtin_amdgcn_mfma_f32_16x16x32_bf16(a0l, b0h.v, c0, 0, 0, 0);
        c1 = __builtin_amdgcn_mfma_f32_16x16x32_bf16(a0l, b1h.v, c1, 0, 0, 0);
        c2 = __builtin_amdgcn_mfma_f32_16x16x32_bf16(a0l, b2h.v, c2, 0, 0, 0);
        c3 = __builtin_amdgcn_mfma_f32_16x16x32_bf16(a0l, b3h.v, c3, 0, 0, 0);
        #pragma unroll
        for (int u = 0; u < 4; ++u) {
            f32x4 cc = (u == 0) ? c0 : (u == 1) ? c1 : (u == 2) ? c2 : c3;
            float rb = Rb1[(g+u) * 16 + l15];
            #pragma unroll
            for (int rg = 0; rg < 4; ++rg)
                T[(quad * 4 + rg) * 260 + (g+u) * 16 + l15] = seluf(cc[rg] + rb);
        }
    }
    __asm__ volatile("s_waitcnt lgkmcnt(0)" ::: "memory");

    bf16x8 h1h[8], h1l[8];
    #pragma unroll
    for (int c = 0; c < 8; ++c) {
        float hv[8];
        const float4* rd = (const float4*)(T + l15 * 260 + c * 32 + quad * 8);
        float4 u0 = rd[0], u1 = rd[1];
        hv[0]=u0.x; hv[1]=u0.y; hv[2]=u0.z; hv[3]=u0.w;
        hv[4]=u1.x; hv[5]=u1.y; hv[6]=u1.z; hv[7]=u1.w;
        split_bf16(hv, h1h[c], h1l[c]);
    }

    // R2: 4 concurrent accumulator chains (16x16 tiles), K-loop inner
    float s[4] = {0.f, 0.f, 0.f, 0.f};
    #pragma unroll 1
    for (int g = 0; g < 16; g += 4) {
        f32x4 a0 = {0.f,0.f,0.f,0.f}, a1 = {0.f,0.f,0.f,0.f};
        f32x4 a2 = {0.f,0.f,0.f,0.f}, a3 = {0.f,0.f,0.f,0.f};
        #pragma unroll
        for (int c = 0; c < 8; ++c) {
            FragCast b0h, b0l, b1h, b1l, b2h, b2l, b3h, b3l;
            b0h.u = r2h[(c * 16 + g + 0) * 64 + lane];
            b0l.u = r2l[(c * 16 + g + 0) * 64 + lane];
            b1h.u = r2h[(c * 16 + g + 1) * 64 + lane];
            b1l.u = r2l[(c * 16 + g + 1) * 64 + lane];
            b2h.u = r2h[(c * 16 + g + 2) * 64 + lane];
            b2l.u = r2l[(c * 16 + g + 2) * 64 + lane];
            b3h.u = r2h[(c * 16 + g + 3) * 64 + lane];
            b3l.u = r2l[(c * 16 + g + 3) * 64 + lane];
            a0 = __builtin_amdgcn_mfma_f32_16x16x32_bf16(h1h[c], b0h.v, a0, 0, 0, 0);
            a1 = __builtin_amdgcn_mfma_f32_16x16x32_bf16(h1h[c], b1h.v, a1, 0, 0, 0);
            a2 = __builtin_amdgcn_mfma_f32_16x16x32_bf16(h1h[c], b2h.v, a2, 0, 0, 0);
            a3 = __builtin_amdgcn_mfma_f32_16x16x32_bf16(h1h[c], b3h.v, a3, 0, 0, 0);
            a0 = __builtin_amdgcn_mfma_f32_16x16x32_bf16(h1h[c], b0l.v, a0, 0, 0, 0);
            a1 = __builtin_amdgcn_mfma_f32_16x16x32_bf16(h1h[c], b1l.v, a1, 0, 0, 0);
            a2 = __builtin_amdgcn_mfma_f32_16x16x32_bf16(h1h[c], b2l.v, a2, 0, 0, 0);
            a3 = __builtin_amdgcn_mfma_f32_16x16x32_bf16(h1h[c], b3l.v, a3, 0, 0, 0);
            a0 = __builtin_amdgcn_mfma_f32_16x16x32_bf16(h1l[c], b0h.v, a0, 0, 0, 0);
            a1 = __builtin_amdgcn_mfma_f32_16x16x32_bf16(h1l[c], b1h.v, a1, 0, 0, 0);
            a2 = __builtin_amdgcn_mfma_f32_16x16x32_bf16(h1l[c], b2h.v, a2, 0, 0, 0);
            a3 = __builtin_amdgcn_mfma_f32_16x16x32_bf16(h1l[c], b3h.v, a3, 0, 0, 0);
        }
        #pragma unroll
        for (int u = 0; u < 4; ++u) {
            f32x4 aa = (u == 0) ? a0 : (u == 1) ? a1 : (u == 2) ? a2 : a3;
            float rb  = Rb2[(g+u) * 16 + l15];
            float r3v = R3[(g+u) * 16 + l15];
            #pragma unroll
            for (int rg = 0; rg < 4; ++rg)
                s[rg] += seluf(aa[rg] + rb) * r3v;
        }
    }
    #pragma unroll
    for (int rg = 0; rg < 4; ++rg) {
        s[rg] += __shfl_xor(s[rg], 1);
        s[rg] += __shfl_xor(s[rg], 2);
        s[rg] += __shfl_xor(s[rg], 4);
        s[rg] += __shfl_xor(s[rg], 8);
    }
    if (l15 == 0) {
        float rb3 = Rb3[0];
        #pragma unroll
        for (int rg = 0; rg < 4; ++rg)
            out[p0 + quad * 4 + rg] = s[rg] + rb3;
    }
}

extern "C" void kernel_launch(void* const* d_in, const int* in_sizes, int n_in,
                              void* d_out, int out_size, void* d_ws, size_t ws_size,
                              hipStream_t stream)
{
    const int*   links = (const int*)d_in[0];
    const float* cap = (const float*)d_in[3];
    const float* pol = (const float*)d_in[4];
    const float* wts = (const float*)d_in[5];
    const float* bw  = (const float*)d_in[6];
    const float* tos = (const float*)d_in[7];
    const float* pk  = (const float*)d_in[8];
    const float* avg = (const float*)d_in[9];
    const float* Wp  = (const float*)d_in[10];
    const float* Up  = (const float*)d_in[11];
    const float* bp  = (const float*)d_in[12];
    const float* Wl  = (const float*)d_in[13];
    const float* Ul  = (const float*)d_in[14];
    const float* bl  = (const float*)d_in[15];
    const float* R1  = (const float*)d_in[16];
    const float* Rb1 = (const float*)d_in[17];
    const float* R2  = (const float*)d_in[18];
    const float* Rb2 = (const float*)d_in[19];
    const float* R3  = (const float*)d_in[20];
    const float* Rb3 = (const float*)d_in[21];

    char* w = (char*)d_ws;
    size_t off = 0;
    auto alloc = [&](size_t bytes) {
        char* p = w + off;
        off += (bytes + 255) & ~(size_t)255;
        return p;
    };
    float*          path_state = (float*)alloc((size_t)NP * DIM * 4);
    float*          link_state = (float*)alloc((size_t)NLINKS * DIM * 4);
    float*          m          = (float*)alloc((size_t)E_TOT * DIM * 4);
    float*          xg         = (float*)alloc((size_t)NLINKS * 128 * 4);
    float*          x_sum      = (float*)alloc((size_t)NLINKS * DIM * 4);
    unsigned short* wfr        = (unsigned short*)alloc(4 * 3072 * 2);
    unsigned short* lfr        = (unsigned short*)alloc(4 * 3072 * 2);
    unsigned short* rfr        = (unsigned short*)alloc((size_t)(8192 + 65536) * 2 * 2);
    int*            cnt        = (int*)alloc((size_t)NLINKS * 4);
    int*            row_start  = (int*)alloc((size_t)(NLINKS + 1) * 4);
    int*            cursor     = (int*)alloc((size_t)NLINKS * 4);
    int*            slot       = (int*)alloc((size_t)E_TOT * 4);

    hipMemsetAsync(cnt, 0, (size_t)NLINKS * 4, stream);
    init_kernel<<<(E_TOT + 255) / 256, 256, 0, stream>>>(links, cap, pol, wts, bw, tos,
                                                         pk, avg, Wp, bp,
                                                         link_state, path_state, xg, cnt);
    prep_kernel<<<1 + 12 + 12 + 288, 256, 0, stream>>>(cnt, row_start, cursor,
                                                       Wp, Up, wfr, Wl, Ul, lfr,
                                                       R1, R2, rfr);
    csr_scatter<<<(E_TOT + 255) / 256, 256, 0, stream>>>(links, cursor, slot);

    const int PGRID = (NP / 16 + 3) / 4;
    const int AGRID = (NLINKS + 3) / 4;
    const int LGRID = (NLINKS / 16 + 3) / 4;
    for (int it = 0; it < TITERS - 1; ++it) {
        path_kernel<<<PGRID, 256, 0, stream>>>(links, xg, wfr, bp,
                                               slot, path_state, m);
        agg_kernel<<<AGRID, 256, 0, stream>>>(row_start, m, x_sum);
        aglk_kernel<<<LGRID, 256, 0, stream>>>(x_sum, lfr, bl, wfr, bp,
                                               link_state, xg);
    }
    readout_kernel<<<(NP / 16 + 1) / 2, 128, 0, stream>>>(links, xg, wfr, bp,
                                                          path_state, rfr, Rb1, Rb2,
                                                          R3, Rb3, (float*)d_out);
}

// Round 6
// 747.506 us; speedup vs baseline: 1.2342x; 1.2342x over previous
//
#include <hip/hip_runtime.h>
#include <hip/hip_bf16.h>

#define NP     100000   // n_paths
#define PLEN   5        // path length
#define NLINKS 10000    // n_links
#define DIM    32       // state dim
#define TITERS 8        // message passing iterations
#define E_TOT  (NP * PLEN)

using bf16x8 = __attribute__((ext_vector_type(8))) short;
using f32x4  = __attribute__((ext_vector_type(4))) float;
union FragCast { uint4 u; bf16x8 v; };

// ---------- helpers ----------
__device__ __forceinline__ float fast_sigmoid(float v) {
    return 1.0f / (1.0f + __expf(-v));
}
__device__ __forceinline__ float fast_tanh(float v) {
    float e = __expf(-2.0f * fabsf(v));
    float t = (1.0f - e) / (1.0f + e);
    return v >= 0.0f ? t : -t;
}
__device__ __forceinline__ float seluf(float v) {
    const float sc = 1.0507009873554805f;
    const float al = 1.6732632423543772f;
    return v > 0.0f ? sc * v : sc * al * (__expf(v) - 1.0f);
}
__device__ __forceinline__ unsigned short f2bf(float f) {
    union { float f; unsigned u; } c; c.f = f;
    unsigned u = c.u;
    return (unsigned short)((u + 0x7fffu + ((u >> 16) & 1u)) >> 16);
}
__device__ __forceinline__ float bf2f(unsigned short b) {
    union { unsigned u; float f; } c; c.u = ((unsigned)b) << 16;
    return c.f;
}
__device__ __forceinline__ void split_bf16(const float (&v)[8], bf16x8& hi, bf16x8& lo) {
    unsigned uh[4], ul[4];
    #pragma unroll
    for (int i = 0; i < 4; ++i) {
        unsigned short h0 = f2bf(v[2*i]),   h1 = f2bf(v[2*i+1]);
        float r0 = v[2*i] - bf2f(h0),       r1 = v[2*i+1] - bf2f(h1);
        unsigned short l0 = f2bf(r0),       l1 = f2bf(r1);
        uh[i] = (unsigned)h0 | ((unsigned)h1 << 16);
        ul[i] = (unsigned)l0 | ((unsigned)l1 << 16);
    }
    FragCast ch, cl;
    ch.u.x = uh[0]; ch.u.y = uh[1]; ch.u.z = uh[2]; ch.u.w = uh[3];
    cl.u.x = ul[0]; cl.u.y = ul[1]; cl.u.z = ul[2]; cl.u.w = ul[3];
    hi = ch.v; lo = cl.v;
}

// ---------- init + CSR count + iteration-0 xg ----------
// xg layout: [link][32][4] = {z, r, n, pad} per state-col, biases folded in.
__global__ __launch_bounds__(256) void init_kernel(
    const int*   __restrict__ links,
    const float* __restrict__ cap, const float* __restrict__ pol, const float* __restrict__ wts,
    const float* __restrict__ bw,  const float* __restrict__ tos,
    const float* __restrict__ pk,  const float* __restrict__ avg,
    const float* __restrict__ Wp,  const float* __restrict__ bp,
    float* __restrict__ link_state, float* __restrict__ path_state,
    float* __restrict__ xg,
    int* __restrict__ cnt)
{
    int i = blockIdx.x * 256 + threadIdx.x;
    if (i < E_TOT) atomicAdd(&cnt[links[i]], 1);
    if (i < NLINKS) {
        float row[DIM];
        #pragma unroll
        for (int c = 0; c < DIM; ++c) row[c] = 0.0f;
        row[0] = cap[i]; row[1] = pol[i]; row[2] = wts[i];
        float4* o = (float4*)(link_state + (size_t)i * DIM);
        #pragma unroll
        for (int c = 0; c < 8; ++c) {
            float4 v = { row[4*c], row[4*c+1], row[4*c+2], row[4*c+3] };
            o[c] = v;
        }
        // xg0 = ls0 @ Wp + folded biases; ls0 has only dims 0..2 nonzero.
        float a = row[0], b = row[1], c3 = row[2];
        float4* xo = (float4*)(xg + (size_t)i * 128);
        #pragma unroll 4
        for (int c = 0; c < 32; ++c) {
            float z = a * Wp[c]      + b * Wp[96+c]  + c3 * Wp[192+c] + bp[c]    + bp[96+c];
            float r = a * Wp[32+c]   + b * Wp[128+c] + c3 * Wp[224+c] + bp[32+c] + bp[128+c];
            float n = a * Wp[64+c]   + b * Wp[160+c] + c3 * Wp[256+c] + bp[64+c];
            float4 v = { z, r, n, 0.0f };
            xo[c] = v;
        }
    }
    if (i < NP) {
        float row[DIM];
        #pragma unroll
        for (int c = 0; c < DIM; ++c) row[c] = 0.0f;
        row[0] = bw[i]; row[1] = tos[i]; row[2] = pk[i]; row[3] = avg[i];
        float4* o = (float4*)(path_state + (size_t)i * DIM);
        #pragma unroll
        for (int c = 0; c < 8; ++c) {
            float4 v = { row[4*c], row[4*c+1], row[4*c+2], row[4*c+3] };
            o[c] = v;
        }
    }
}

// ---------- prep item helpers ----------
__device__ __forceinline__ void wprep_item(const float* __restrict__ W,
                                           const float* __restrict__ U,
                                           unsigned short* __restrict__ ofr, int idx)
{
    int j = idx & 7, lane = (idx >> 3) & 63, g = idx >> 9;
    int k = (lane >> 4) * 8 + j;
    int n = g * 16 + (lane & 15);
    float w = W[k * 96 + n];
    float u = U[k * 96 + n];
    unsigned short whi = f2bf(w); unsigned short wlo = f2bf(w - bf2f(whi));
    unsigned short uhi = f2bf(u); unsigned short ulo = f2bf(u - bf2f(uhi));
    ofr[0 * 3072 + idx] = whi;
    ofr[1 * 3072 + idx] = wlo;
    ofr[2 * 3072 + idx] = uhi;
    ofr[3 * 3072 + idx] = ulo;
}

__device__ __forceinline__ void rprep_item(const float* __restrict__ R1,
                                           const float* __restrict__ R2,
                                           unsigned short* __restrict__ rfr, int idx)
{
    if (idx < 8192) {
        int j = idx & 7, lane = (idx >> 3) & 63, g = idx >> 9;
        int k = (lane >> 4) * 8 + j;
        int n = g * 16 + (lane & 15);
        float v = R1[k * 256 + n];
        unsigned short hi = f2bf(v);
        rfr[idx] = hi;
        rfr[8192 + idx] = f2bf(v - bf2f(hi));
    } else {
        int idx2 = idx - 8192;
        int j = idx2 & 7, lane = (idx2 >> 3) & 63, tile = idx2 >> 9;
        int c = tile >> 4, g = tile & 15;
        int k = c * 32 + (lane >> 4) * 8 + j;
        int n = g * 16 + (lane & 15);
        float v = R2[k * 256 + n];
        unsigned short hi = f2bf(v);
        rfr[16384 + idx2] = hi;
        rfr[16384 + 65536 + idx2] = f2bf(v - bf2f(hi));
    }
}

// ---------- merged prep: block 0 = CSR scan; blocks 1.. = weight frag prep ----
__global__ __launch_bounds__(256) void prep_kernel(
    const int*   __restrict__ cnt,
    int* __restrict__ row_start, int* __restrict__ cursor,
    const float* __restrict__ Wp, const float* __restrict__ Up,
    unsigned short* __restrict__ wfr,
    const float* __restrict__ Wl, const float* __restrict__ Ul,
    unsigned short* __restrict__ lfr,
    const float* __restrict__ R1, const float* __restrict__ R2,
    unsigned short* __restrict__ rfr)
{
    int t = threadIdx.x;
    if (blockIdx.x == 0) {
        __shared__ int s[256];
        const int CH = (NLINKS + 255) / 256;   // 40
        int base = t * CH;
        int sum = 0;
        for (int i = 0; i < CH; ++i) {
            int idx = base + i;
            if (idx < NLINKS) sum += cnt[idx];
        }
        s[t] = sum;
        __syncthreads();
        for (int off = 1; off < 256; off <<= 1) {
            int v = (t >= off) ? s[t - off] : 0;
            __syncthreads();
            s[t] += v;
            __syncthreads();
        }
        int run = s[t] - sum;
        for (int i = 0; i < CH; ++i) {
            int idx = base + i;
            if (idx < NLINKS) {
                row_start[idx] = run;
                cursor[idx]    = run;
                run += cnt[idx];
            }
        }
        if (t == 255) row_start[NLINKS] = s[255];
        return;
    }
    int idx = (blockIdx.x - 1) * 256 + t;
    if (idx < 3072) {
        wprep_item(Wp, Up, wfr, idx);
    } else if (idx < 6144) {
        wprep_item(Wl, Ul, lfr, idx - 3072);
    } else if (idx < 6144 + 8192 + 65536) {
        rprep_item(R1, R2, rfr, idx - 6144);
    }
}

__global__ __launch_bounds__(256) void csr_scatter(const int* __restrict__ links,
                                                   int* __restrict__ cursor,
                                                   int* __restrict__ slot)
{
    int e = blockIdx.x * 256 + threadIdx.x;
    if (e < E_TOT) slot[e] = atomicAdd(&cursor[links[e]], 1);
}

// ---------- shared device body: 5-hop MFMA path GRU for one 16-path tile ----
// (round-4 proven form: natural operands, LDS transpose per hop)
template <bool STORE_M>
__device__ __forceinline__ void path_gru_body(
    int p0, int l15, int quad, float* T,
    const int* __restrict__ links,
    const float* __restrict__ xg,
    const unsigned short* __restrict__ wfr,
    const float* __restrict__ bp,
    const int* __restrict__ slot,
    const float* __restrict__ path_state,
    float* __restrict__ m,
    float (&hA)[8])
{
    int lane = quad * 16 + l15;
    int p = p0 + l15;
    int sl[PLEN];
    if (STORE_M) {
        #pragma unroll
        for (int l = 0; l < PLEN; ++l) sl[l] = slot[p * PLEN + l];
    }

    // link ids for the 4 acc-row paths, all hops (feeds the xv gathers)
    int lk[PLEN][4];
    #pragma unroll
    for (int rg = 0; rg < 4; ++rg) {
        int pb = (p0 + quad * 4 + rg) * PLEN;
        #pragma unroll
        for (int l = 0; l < PLEN; ++l) lk[l][rg] = links[pb + l];
    }

    // U fragments only (hi/lo)
    bf16x8 Uh[6], Ul[6];
    {
        const uint4* base = (const uint4*)wfr;
        #pragma unroll
        for (int g = 0; g < 6; ++g) {
            FragCast a;
            a.u = base[2 * 384 + g * 64 + lane]; Uh[g] = a.v;
            a.u = base[3 * 384 + g * 64 + lane]; Ul[g] = a.v;
        }
    }
    float bnh[2];
    #pragma unroll
    for (int hf = 0; hf < 2; ++hf) bnh[hf] = bp[96 + 64 + hf * 16 + l15];

    {
        const float4* src = (const float4*)(path_state + (size_t)p * DIM + quad * 8);
        float4 v0 = src[0], v1 = src[1];
        hA[0]=v0.x; hA[1]=v0.y; hA[2]=v0.z; hA[3]=v0.w;
        hA[4]=v1.x; hA[5]=v1.y; hA[6]=v1.z; hA[7]=v1.w;
    }
    #pragma unroll
    for (int j = 0; j < 8; ++j) T[l15 * 36 + quad * 8 + j] = hA[j];
    __asm__ volatile("s_waitcnt lgkmcnt(0)" ::: "memory");
    float hC[2][4];
    #pragma unroll
    for (int hf = 0; hf < 2; ++hf)
        #pragma unroll
        for (int rg = 0; rg < 4; ++rg)
            hC[hf][rg] = T[(quad * 4 + rg) * 36 + hf * 16 + l15];

    bf16x8 ah, al;
    split_bf16(hA, ah, al);

    #pragma unroll
    for (int l = 0; l < PLEN; ++l) {
        // gather precomputed gate pre-activations for the 4 acc-row paths
        float4 xv[2][4];
        #pragma unroll
        for (int rg = 0; rg < 4; ++rg) {
            const float4* xp = (const float4*)(xg + (size_t)lk[l][rg] * 128);
            xv[0][rg] = xp[l15];
            xv[1][rg] = xp[16 + l15];
        }
        #pragma unroll
        for (int hf = 0; hf < 2; ++hf) {
            f32x4 az  = { xv[hf][0].x, xv[hf][1].x, xv[hf][2].x, xv[hf][3].x };
            f32x4 ar  = { xv[hf][0].y, xv[hf][1].y, xv[hf][2].y, xv[hf][3].y };
            f32x4 ahg = { 0.f, 0.f, 0.f, 0.f };
            int gz = hf, gr = 2 + hf, gn = 4 + hf;
            az  = __builtin_amdgcn_mfma_f32_16x16x32_bf16(ah, Uh[gz], az,  0, 0, 0);
            ar  = __builtin_amdgcn_mfma_f32_16x16x32_bf16(ah, Uh[gr], ar,  0, 0, 0);
            ahg = __builtin_amdgcn_mfma_f32_16x16x32_bf16(ah, Uh[gn], ahg, 0, 0, 0);
            az  = __builtin_amdgcn_mfma_f32_16x16x32_bf16(ah, Ul[gz], az,  0, 0, 0);
            ar  = __builtin_amdgcn_mfma_f32_16x16x32_bf16(ah, Ul[gr], ar,  0, 0, 0);
            ahg = __builtin_amdgcn_mfma_f32_16x16x32_bf16(ah, Ul[gn], ahg, 0, 0, 0);
            az  = __builtin_amdgcn_mfma_f32_16x16x32_bf16(al, Uh[gz], az,  0, 0, 0);
            ar  = __builtin_amdgcn_mfma_f32_16x16x32_bf16(al, Uh[gr], ar,  0, 0, 0);
            ahg = __builtin_amdgcn_mfma_f32_16x16x32_bf16(al, Uh[gn], ahg, 0, 0, 0);
            #pragma unroll
            for (int rg = 0; rg < 4; ++rg) {
                float z  = fast_sigmoid(az[rg]);
                float r  = fast_sigmoid(ar[rg]);
                float hn = fast_tanh(xv[hf][rg].z + r * (ahg[rg] + bnh[hf]));
                hC[hf][rg] = z * hC[hf][rg] + (1.0f - z) * hn;
            }
        }

        __asm__ volatile("s_waitcnt lgkmcnt(0)" ::: "memory");
        #pragma unroll
        for (int hf = 0; hf < 2; ++hf)
            #pragma unroll
            for (int rg = 0; rg < 4; ++rg)
                T[(quad * 4 + rg) * 36 + hf * 16 + l15] = hC[hf][rg];
        __asm__ volatile("s_waitcnt lgkmcnt(0)" ::: "memory");
        {
            const float4* rd = (const float4*)(T + l15 * 36 + quad * 8);
            float4 v0 = rd[0], v1 = rd[1];
            hA[0]=v0.x; hA[1]=v0.y; hA[2]=v0.z; hA[3]=v0.w;
            hA[4]=v1.x; hA[5]=v1.y; hA[6]=v1.z; hA[7]=v1.w;
        }
        if (STORE_M) {
            float4* dst = (float4*)(m + (size_t)sl[l] * DIM + quad * 8);
            float4 v0 = { hA[0], hA[1], hA[2], hA[3] };
            float4 v1 = { hA[4], hA[5], hA[6], hA[7] };
            dst[0] = v0; dst[1] = v1;
        }
        if (l < PLEN - 1) split_bf16(hA, ah, al);
    }
}

// ---------- MFMA path GRU kernel (iterations 0..6) ----------
__global__ __launch_bounds__(256) void path_kernel(
    const int*   __restrict__ links,
    const float* __restrict__ xg,
    const unsigned short* __restrict__ wfr,
    const float* __restrict__ bp,
    const int*   __restrict__ slot,
    float* __restrict__ path_state,
    float* __restrict__ m)
{
    __shared__ __align__(16) float T4[4][16 * 36];
    int t = threadIdx.x;
    int wave = t >> 6, lane = t & 63;
    int l15 = lane & 15, quad = lane >> 4;
    int p0 = (blockIdx.x * 4 + wave) * 16;
    if (p0 >= NP) return;
    int p = p0 + l15;
    float hA[8];
    path_gru_body<true>(p0, l15, quad, T4[wave], links, xg, wfr, bp,
                        slot, path_state, m, hA);
    float4* ho = (float4*)(path_state + (size_t)p * DIM + quad * 8);
    float4 v0 = { hA[0], hA[1], hA[2], hA[3] };
    float4 v1 = { hA[4], hA[5], hA[6], hA[7] };
    ho[0] = v0; ho[1] = v1;
}

// ---------- segment-sum: one wave per link, coalesced CSR-ordered read ----
__global__ __launch_bounds__(256) void agg_kernel(
    const int* __restrict__ row_start,
    const float* __restrict__ m,
    float* __restrict__ x_sum)
{
    int t = threadIdx.x;
    int wave = t >> 6, lane = t & 63;
    int link = blockIdx.x * 4 + wave;
    if (link >= NLINKS) return;
    int r = lane >> 3;
    int c = lane & 7;
    int s0 = row_start[link], s1 = row_start[link + 1];
    float4 acc = {0.f, 0.f, 0.f, 0.f};
    for (int i = s0 + r; i < s1; i += 8) {
        const float4 v = *(const float4*)(m + (size_t)i * DIM + c * 4);
        acc.x += v.x; acc.y += v.y; acc.z += v.z; acc.w += v.w;
    }
    #pragma unroll
    for (int off = 8; off < 64; off <<= 1) {
        acc.x += __shfl_xor(acc.x, off);
        acc.y += __shfl_xor(acc.y, off);
        acc.z += __shfl_xor(acc.z, off);
        acc.w += __shfl_xor(acc.w, off);
    }
    if (r == 0)
        *(float4*)(x_sum + (size_t)link * DIM + c * 4) = acc;
}

// ---------- link GRU: dense x_sum read, link_state update, next xg ----------
__global__ __launch_bounds__(256) void aglk_kernel(
    const float* __restrict__ x_sum,
    const unsigned short* __restrict__ lfr,
    const float* __restrict__ bl,
    const unsigned short* __restrict__ wfr,
    const float* __restrict__ bp,
    float* __restrict__ link_state,
    float* __restrict__ xg)
{
    __shared__ __align__(16) float T4[4][16 * 36];
    int t = threadIdx.x;
    int wave = t >> 6, lane = t & 63;
    int l15 = lane & 15, quad = lane >> 4;
    int lb = (blockIdx.x * 4 + wave) * 16;
    if (lb >= NLINKS) return;
    float* T = T4[wave];
    int link = lb + l15;

    bf16x8 Wh[6], Wlo[6], Uh[6], Ulo[6];
    {
        const uint4* base = (const uint4*)lfr;
        #pragma unroll
        for (int g = 0; g < 6; ++g) {
            FragCast a;
            a.u = base[0 * 384 + g * 64 + lane]; Wh[g]  = a.v;
            a.u = base[1 * 384 + g * 64 + lane]; Wlo[g] = a.v;
            a.u = base[2 * 384 + g * 64 + lane]; Uh[g]  = a.v;
            a.u = base[3 * 384 + g * 64 + lane]; Ulo[g] = a.v;
        }
    }
    float bz[2], br[2], bnx[2], bnh[2];
    #pragma unroll
    for (int hf = 0; hf < 2; ++hf) {
        int c = hf * 16 + l15;
        bz[hf]  = bl[c]      + bl[96 + c];
        br[hf]  = bl[32 + c] + bl[96 + 32 + c];
        bnx[hf] = bl[64 + c];
        bnh[hf] = bl[96 + 64 + c];
    }

    float x8[8];
    {
        const float4* xs = (const float4*)(x_sum + (size_t)link * DIM + quad * 8);
        float4 a = xs[0], b = xs[1];
        x8[0]=a.x; x8[1]=a.y; x8[2]=a.z; x8[3]=a.w;
        x8[4]=b.x; x8[5]=b.y; x8[6]=b.z; x8[7]=b.w;
    }
    bf16x8 xh, xl;
    split_bf16(x8, xh, xl);

    float hA[8];
    {
        const float4* src = (const float4*)(link_state + (size_t)link * DIM + quad * 8);
        float4 v0 = src[0], v1 = src[1];
        hA[0]=v0.x; hA[1]=v0.y; hA[2]=v0.z; hA[3]=v0.w;
        hA[4]=v1.x; hA[5]=v1.y; hA[6]=v1.z; hA[7]=v1.w;
    }
    #pragma unroll
    for (int j = 0; j < 8; ++j) T[l15 * 36 + quad * 8 + j] = hA[j];
    __asm__ volatile("s_waitcnt lgkmcnt(0)" ::: "memory");
    float hC[2][4];
    #pragma unroll
    for (int hf = 0; hf < 2; ++hf)
        #pragma unroll
        for (int rg = 0; rg < 4; ++rg)
            hC[hf][rg] = T[(quad * 4 + rg) * 36 + hf * 16 + l15];
    bf16x8 ah, al;
    split_bf16(hA, ah, al);

    #pragma unroll
    for (int hf = 0; hf < 2; ++hf) {
        f32x4 az = {0.f,0.f,0.f,0.f}, ar = {0.f,0.f,0.f,0.f};
        f32x4 axn = {0.f,0.f,0.f,0.f}, ahg = {0.f,0.f,0.f,0.f};
        int gz = hf, gr = 2 + hf, gn = 4 + hf;
        az = __builtin_amdgcn_mfma_f32_16x16x32_bf16(xh, Wh[gz],  az, 0, 0, 0);
        az = __builtin_amdgcn_mfma_f32_16x16x32_bf16(xh, Wlo[gz], az, 0, 0, 0);
        az = __builtin_amdgcn_mfma_f32_16x16x32_bf16(xl, Wh[gz],  az, 0, 0, 0);
        az = __builtin_amdgcn_mfma_f32_16x16x32_bf16(ah, Uh[gz],  az, 0, 0, 0);
        az = __builtin_amdgcn_mfma_f32_16x16x32_bf16(ah, Ulo[gz], az, 0, 0, 0);
        az = __builtin_amdgcn_mfma_f32_16x16x32_bf16(al, Uh[gz],  az, 0, 0, 0);
        ar = __builtin_amdgcn_mfma_f32_16x16x32_bf16(xh, Wh[gr],  ar, 0, 0, 0);
        ar = __builtin_amdgcn_mfma_f32_16x16x32_bf16(xh, Wlo[gr], ar, 0, 0, 0);
        ar = __builtin_amdgcn_mfma_f32_16x16x32_bf16(xl, Wh[gr],  ar, 0, 0, 0);
        ar = __builtin_amdgcn_mfma_f32_16x16x32_bf16(ah, Uh[gr],  ar, 0, 0, 0);
        ar = __builtin_amdgcn_mfma_f32_16x16x32_bf16(ah, Ulo[gr], ar, 0, 0, 0);
        ar = __builtin_amdgcn_mfma_f32_16x16x32_bf16(al, Uh[gr],  ar, 0, 0, 0);
        axn = __builtin_amdgcn_mfma_f32_16x16x32_bf16(xh, Wh[gn],  axn, 0, 0, 0);
        axn = __builtin_amdgcn_mfma_f32_16x16x32_bf16(xh, Wlo[gn], axn, 0, 0, 0);
        axn = __builtin_amdgcn_mfma_f32_16x16x32_bf16(xl, Wh[gn],  axn, 0, 0, 0);
        ahg = __builtin_amdgcn_mfma_f32_16x16x32_bf16(ah, Uh[gn],  ahg, 0, 0, 0);
        ahg = __builtin_amdgcn_mfma_f32_16x16x32_bf16(ah, Ulo[gn], ahg, 0, 0, 0);
        ahg = __builtin_amdgcn_mfma_f32_16x16x32_bf16(al, Uh[gn],  ahg, 0, 0, 0);
        #pragma unroll
        for (int rg = 0; rg < 4; ++rg) {
            float z  = fast_sigmoid(az[rg] + bz[hf]);
            float r  = fast_sigmoid(ar[rg] + br[hf]);
            float hn = fast_tanh(axn[rg] + bnx[hf] + r * (ahg[rg] + bnh[hf]));
            hC[hf][rg] = z * hC[hf][rg] + (1.0f - z) * hn;
        }
    }

    __asm__ volatile("s_waitcnt lgkmcnt(0)" ::: "memory");
    #pragma unroll
    for (int hf = 0; hf < 2; ++hf)
        #pragma unroll
        for (int rg = 0; rg < 4; ++rg)
            T[(quad * 4 + rg) * 36 + hf * 16 + l15] = hC[hf][rg];
    __asm__ volatile("s_waitcnt lgkmcnt(0)" ::: "memory");
    {
        const float4* rd = (const float4*)(T + l15 * 36 + quad * 8);
        float4 v0 = rd[0], v1 = rd[1];
        hA[0]=v0.x; hA[1]=v0.y; hA[2]=v0.z; hA[3]=v0.w;
        hA[4]=v1.x; hA[5]=v1.y; hA[6]=v1.z; hA[7]=v1.w;
    }
    float4* ho = (float4*)(link_state + (size_t)link * DIM + quad * 8);
    float4 v0 = { hA[0], hA[1], hA[2], hA[3] };
    float4 v1 = { hA[4], hA[5], hA[6], hA[7] };
    ho[0] = v0; ho[1] = v1;

    // ---- xg for next path iteration: new_h @ Wp + folded path biases ----
    bf16x8 nh, nl;
    split_bf16(hA, nh, nl);
    {
        const uint4* wb = (const uint4*)wfr;
        #pragma unroll
        for (int hf2 = 0; hf2 < 2; ++hf2) {
            int c0 = hf2 * 16 + l15;
            float foldz = bp[c0]      + bp[96 + c0];
            float foldr = bp[32 + c0] + bp[128 + c0];
            float foldn = bp[64 + c0];
            FragCast wzh, wzl, wrh, wrl, wnh, wnl;
            wzh.u = wb[0 * 384 + (hf2)     * 64 + lane];
            wzl.u = wb[1 * 384 + (hf2)     * 64 + lane];
            wrh.u = wb[0 * 384 + (2 + hf2) * 64 + lane];
            wrl.u = wb[1 * 384 + (2 + hf2) * 64 + lane];
            wnh.u = wb[0 * 384 + (4 + hf2) * 64 + lane];
            wnl.u = wb[1 * 384 + (4 + hf2) * 64 + lane];
            f32x4 cz = {0.f,0.f,0.f,0.f}, cr = {0.f,0.f,0.f,0.f}, cn = {0.f,0.f,0.f,0.f};
            cz = __builtin_amdgcn_mfma_f32_16x16x32_bf16(nh, wzh.v, cz, 0, 0, 0);
            cr = __builtin_amdgcn_mfma_f32_16x16x32_bf16(nh, wrh.v, cr, 0, 0, 0);
            cn = __builtin_amdgcn_mfma_f32_16x16x32_bf16(nh, wnh.v, cn, 0, 0, 0);
            cz = __builtin_amdgcn_mfma_f32_16x16x32_bf16(nh, wzl.v, cz, 0, 0, 0);
            cr = __builtin_amdgcn_mfma_f32_16x16x32_bf16(nh, wrl.v, cr, 0, 0, 0);
            cn = __builtin_amdgcn_mfma_f32_16x16x32_bf16(nh, wnl.v, cn, 0, 0, 0);
            cz = __builtin_amdgcn_mfma_f32_16x16x32_bf16(nl, wzh.v, cz, 0, 0, 0);
            cr = __builtin_amdgcn_mfma_f32_16x16x32_bf16(nl, wrh.v, cr, 0, 0, 0);
            cn = __builtin_amdgcn_mfma_f32_16x16x32_bf16(nl, wnh.v, cn, 0, 0, 0);
            #pragma unroll
            for (int rg = 0; rg < 4; ++rg) {
                float4 v = { cz[rg] + foldz, cr[rg] + foldr, cn[rg] + foldn, 0.f };
                *(float4*)(xg + (size_t)(lb + quad * 4 + rg) * 128 + c0 * 4) = v;
            }
        }
    }
}

// ---------- fused: final path GRU iteration + MFMA readout ----------
// Readout uses swapped-operand chaining: h0 (B-layout from GRU) -> R1 as
// mfma(R1^T-frag, h0) -> quad-butterfly (2 shfl_xor) into B-frags of h1 ->
// R2 as mfma(R2^T-frag, h1) -> per-lane dot with R3, quad reduce.
// No h1 LDS buffer, no lgkmcnt drains after the GRU.
__global__ __launch_bounds__(128, 1) void readout_kernel(
    const int*   __restrict__ links,
    const float* __restrict__ xg,
    const unsigned short* __restrict__ wfr,
    const float* __restrict__ bp,
    const float* __restrict__ path_state,
    const unsigned short* __restrict__ rfr,
    const float* __restrict__ Rb1, const float* __restrict__ Rb2,
    const float* __restrict__ R3,  const float* __restrict__ Rb3,
    float* __restrict__ out)
{
    __shared__ __align__(16) float T2[2][16 * 36];
    int t = threadIdx.x;
    int wave = t >> 6, lane = t & 63;
    int l15 = lane & 15, quad = lane >> 4;
    int p0 = (blockIdx.x * 2 + wave) * 16;
    if (p0 >= NP) return;
    float* T = T2[wave];

    float h0[8];
    path_gru_body<false>(p0, l15, quad, T, links, xg, wfr, bp,
                         nullptr, path_state, nullptr, h0);

    const uint4* r1h = (const uint4*)rfr;
    const uint4* r1l = r1h + 1024;
    const uint4* r2h = r1l + 1024;
    const uint4* r2l = r2h + 8192;

    // h0 is already a B fragment (k=dim chunk quad, n=path l15)
    bf16x8 b0h, b0l;
    split_bf16(h0, b0h, b0l);

    // R1 swapped: per c-chunk, chains g=2c (even) and 2c+1 (odd); exchange
    // outputs across quads into B-fragments bh/bl[c] of h1 (k-dims c*32..+31).
    bf16x8 bh[8], bl[8];
    #pragma unroll
    for (int c = 0; c < 8; ++c) {
        FragCast feh, fel, foh, fol;
        feh.u = r1h[(2*c)   * 64 + lane]; fel.u = r1l[(2*c)   * 64 + lane];
        foh.u = r1h[(2*c+1) * 64 + lane]; fol.u = r1l[(2*c+1) * 64 + lane];
        f32x4 ce = {0.f,0.f,0.f,0.f}, co = {0.f,0.f,0.f,0.f};
        ce = __builtin_amdgcn_mfma_f32_16x16x32_bf16(feh.v, b0h, ce, 0, 0, 0);
        co = __builtin_amdgcn_mfma_f32_16x16x32_bf16(foh.v, b0h, co, 0, 0, 0);
        ce = __builtin_amdgcn_mfma_f32_16x16x32_bf16(feh.v, b0l, ce, 0, 0, 0);
        co = __builtin_amdgcn_mfma_f32_16x16x32_bf16(foh.v, b0l, co, 0, 0, 0);
        ce = __builtin_amdgcn_mfma_f32_16x16x32_bf16(fel.v, b0h, ce, 0, 0, 0);
        co = __builtin_amdgcn_mfma_f32_16x16x32_bf16(fol.v, b0h, co, 0, 0, 0);
        float rbe[4], rbo[4];
        {
            float4 v0 = *(const float4*)(Rb1 + c * 32 + quad * 4);
            float4 v1 = *(const float4*)(Rb1 + c * 32 + 16 + quad * 4);
            rbe[0]=v0.x; rbe[1]=v0.y; rbe[2]=v0.z; rbe[3]=v0.w;
            rbo[0]=v1.x; rbo[1]=v1.y; rbo[2]=v1.z; rbo[3]=v1.w;
        }
        float o8[8];
        #pragma unroll
        for (int rg = 0; rg < 4; ++rg) {
            float e = seluf(ce[rg] + rbe[rg]);   // h1[c*32 + quad*4 + rg]
            float o = seluf(co[rg] + rbo[rg]);   // h1[c*32 + 16 + quad*4 + rg]
            // stage 1 (xor 32): even values to quads {0,1}, odd to {2,3}
            float s1 = (quad < 2) ? o : e;
            float r1v = __shfl_xor(s1, 32);
            float x = (quad < 2) ? e : r1v;
            float y = (quad < 2) ? r1v : o;
            // stage 2 (xor 16): order halves within each pair
            float s2 = ((quad & 1) == 0) ? y : x;
            float r2v = __shfl_xor(s2, 16);
            o8[rg]     = ((quad & 1) == 0) ? x : r2v;  // h1[c*32+quad*8+rg]
            o8[4 + rg] = ((quad & 1) == 0) ? r2v : y;  // h1[c*32+quad*8+4+rg]
        }
        split_bf16(o8, bh[c], bl[c]);
    }

    // R2 swapped: 4 concurrent chains over out-dim groups g; A-frags streamed
    // from rfr, B = bh/bl registers. s = per-lane (path l15) partial dot.
    float s = 0.f;
    #pragma unroll 1
    for (int g = 0; g < 16; g += 4) {
        f32x4 a0 = {0.f,0.f,0.f,0.f}, a1 = {0.f,0.f,0.f,0.f};
        f32x4 a2 = {0.f,0.f,0.f,0.f}, a3 = {0.f,0.f,0.f,0.f};
        #pragma unroll
        for (int c = 0; c < 8; ++c) {
            FragCast f0h, f0l, f1h, f1l, f2h, f2l, f3h, f3l;
            f0h.u = r2h[(c * 16 + g + 0) * 64 + lane];
            f0l.u = r2l[(c * 16 + g + 0) * 64 + lane];
            f1h.u = r2h[(c * 16 + g + 1) * 64 + lane];
            f1l.u = r2l[(c * 16 + g + 1) * 64 + lane];
            f2h.u = r2h[(c * 16 + g + 2) * 64 + lane];
            f2l.u = r2l[(c * 16 + g + 2) * 64 + lane];
            f3h.u = r2h[(c * 16 + g + 3) * 64 + lane];
            f3l.u = r2l[(c * 16 + g + 3) * 64 + lane];
            a0 = __builtin_amdgcn_mfma_f32_16x16x32_bf16(f0h.v, bh[c], a0, 0, 0, 0);
            a1 = __builtin_amdgcn_mfma_f32_16x16x32_bf16(f1h.v, bh[c], a1, 0, 0, 0);
            a2 = __builtin_amdgcn_mfma_f32_16x16x32_bf16(f2h.v, bh[c], a2, 0, 0, 0);
            a3 = __builtin_amdgcn_mfma_f32_16x16x32_bf16(f3h.v, bh[c], a3, 0, 0, 0);
            a0 = __builtin_amdgcn_mfma_f32_16x16x32_bf16(f0l.v, bh[c], a0, 0, 0, 0);
            a1 = __builtin_amdgcn_mfma_f32_16x16x32_bf16(f1l.v, bh[c], a1, 0, 0, 0);
            a2 = __builtin_amdgcn_mfma_f32_16x16x32_bf16(f2l.v, bh[c], a2, 0, 0, 0);
            a3 = __builtin_amdgcn_mfma_f32_16x16x32_bf16(f3l.v, bh[c], a3, 0, 0, 0);
            a0 = __builtin_amdgcn_mfma_f32_16x16x32_bf16(f0h.v, bl[c], a0, 0, 0, 0);
            a1 = __builtin_amdgcn_mfma_f32_16x16x32_bf16(f1h.v, bl[c], a1, 0, 0, 0);
            a2 = __builtin_amdgcn_mfma_f32_16x16x32_bf16(f2h.v, bl[c], a2, 0, 0, 0);
            a3 = __builtin_amdgcn_mfma_f32_16x16x32_bf16(f3h.v, bl[c], a3, 0, 0, 0);
        }
        #pragma unroll
        for (int u = 0; u < 4; ++u) {
            f32x4 aa = (u == 0) ? a0 : (u == 1) ? a1 : (u == 2) ? a2 : a3;
            float rb2[4], r3v[4];
            {
                float4 vb = *(const float4*)(Rb2 + (g + u) * 16 + quad * 4);
                float4 vr = *(const float4*)(R3  + (g + u) * 16 + quad * 4);
                rb2[0]=vb.x; rb2[1]=vb.y; rb2[2]=vb.z; rb2[3]=vb.w;
                r3v[0]=vr.x; r3v[1]=vr.y; r3v[2]=vr.z; r3v[3]=vr.w;
            }
            #pragma unroll
            for (int rg = 0; rg < 4; ++rg)
                s += seluf(aa[rg] + rb2[rg]) * r3v[rg];
        }
    }
    // reduce partial dots across the 4 quads (same path l15)
    s += __shfl_xor(s, 16);
    s += __shfl_xor(s, 32);
    if (quad == 0)
        out[p0 + l15] = s + Rb3[0];
}

extern "C" void kernel_launch(void* const* d_in, const int* in_sizes, int n_in,
                              void* d_out, int out_size, void* d_ws, size_t ws_size,
                              hipStream_t stream)
{
    const int*   links = (const int*)d_in[0];
    const float* cap = (const float*)d_in[3];
    const float* pol = (const float*)d_in[4];
    const float* wts = (const float*)d_in[5];
    const float* bw  = (const float*)d_in[6];
    const float* tos = (const float*)d_in[7];
    const float* pk  = (const float*)d_in[8];
    const float* avg = (const float*)d_in[9];
    const float* Wp  = (const float*)d_in[10];
    const float* Up  = (const float*)d_in[11];
    const float* bp  = (const float*)d_in[12];
    const float* Wl  = (const float*)d_in[13];
    const float* Ul  = (const float*)d_in[14];
    const float* bl  = (const float*)d_in[15];
    const float* R1  = (const float*)d_in[16];
    const float* Rb1 = (const float*)d_in[17];
    const float* R2  = (const float*)d_in[18];
    const float* Rb2 = (const float*)d_in[19];
    const float* R3  = (const float*)d_in[20];
    const float* Rb3 = (const float*)d_in[21];

    char* w = (char*)d_ws;
    size_t off = 0;
    auto alloc = [&](size_t bytes) {
        char* p = w + off;
        off += (bytes + 255) & ~(size_t)255;
        return p;
    };
    float*          path_state = (float*)alloc((size_t)NP * DIM * 4);
    float*          link_state = (float*)alloc((size_t)NLINKS * DIM * 4);
    float*          m          = (float*)alloc((size_t)E_TOT * DIM * 4);
    float*          xg         = (float*)alloc((size_t)NLINKS * 128 * 4);
    float*          x_sum      = (float*)alloc((size_t)NLINKS * DIM * 4);
    unsigned short* wfr        = (unsigned short*)alloc(4 * 3072 * 2);
    unsigned short* lfr        = (unsigned short*)alloc(4 * 3072 * 2);
    unsigned short* rfr        = (unsigned short*)alloc((size_t)(8192 + 65536) * 2 * 2);
    int*            cnt        = (int*)alloc((size_t)NLINKS * 4);
    int*            row_start  = (int*)alloc((size_t)(NLINKS + 1) * 4);
    int*            cursor     = (int*)alloc((size_t)NLINKS * 4);
    int*            slot       = (int*)alloc((size_t)E_TOT * 4);

    hipMemsetAsync(cnt, 0, (size_t)NLINKS * 4, stream);
    init_kernel<<<(E_TOT + 255) / 256, 256, 0, stream>>>(links, cap, pol, wts, bw, tos,
                                                         pk, avg, Wp, bp,
                                                         link_state, path_state, xg, cnt);
    prep_kernel<<<1 + 12 + 12 + 288, 256, 0, stream>>>(cnt, row_start, cursor,
                                                       Wp, Up, wfr, Wl, Ul, lfr,
                                                       R1, R2, rfr);
    csr_scatter<<<(E_TOT + 255) / 256, 256, 0, stream>>>(links, cursor, slot);

    const int PGRID = (NP / 16 + 3) / 4;
    const int AGRID = (NLINKS + 3) / 4;
    const int LGRID = (NLINKS / 16 + 3) / 4;
    for (int it = 0; it < TITERS - 1; ++it) {
        path_kernel<<<PGRID, 256, 0, stream>>>(links, xg, wfr, bp,
                                               slot, path_state, m);
        agg_kernel<<<AGRID, 256, 0, stream>>>(row_start, m, x_sum);
        aglk_kernel<<<LGRID, 256, 0, stream>>>(x_sum, lfr, bl, wfr, bp,
                                               link_state, xg);
    }
    readout_kernel<<<(NP / 16 + 1) / 2, 128, 0, stream>>>(links, xg, wfr, bp,
                                                          path_state, rfr, Rb1, Rb2,
                                                          R3, Rb3, (float*)d_out);
}

// Round 7
// 743.844 us; speedup vs baseline: 1.2402x; 1.0049x over previous
//
#include <hip/hip_runtime.h>
#include <hip/hip_bf16.h>

#define NP     100000   // n_paths
#define PLEN   5        // path length
#define NLINKS 10000    // n_links
#define DIM    32       // state dim
#define TITERS 8        // message passing iterations
#define E_TOT  (NP * PLEN)

using bf16x8 = __attribute__((ext_vector_type(8))) short;
using f32x4  = __attribute__((ext_vector_type(4))) float;
union FragCast { uint4 u; bf16x8 v; };

// ---------- helpers ----------
__device__ __forceinline__ float fast_sigmoid(float v) {
    return 1.0f / (1.0f + __expf(-v));
}
__device__ __forceinline__ float fast_tanh(float v) {
    float e = __expf(-2.0f * fabsf(v));
    float t = (1.0f - e) / (1.0f + e);
    return v >= 0.0f ? t : -t;
}
__device__ __forceinline__ float seluf(float v) {
    const float sc = 1.0507009873554805f;
    const float al = 1.6732632423543772f;
    return v > 0.0f ? sc * v : sc * al * (__expf(v) - 1.0f);
}
__device__ __forceinline__ unsigned short f2bf(float f) {
    union { float f; unsigned u; } c; c.f = f;
    unsigned u = c.u;
    return (unsigned short)((u + 0x7fffu + ((u >> 16) & 1u)) >> 16);
}
__device__ __forceinline__ float bf2f(unsigned short b) {
    union { unsigned u; float f; } c; c.u = ((unsigned)b) << 16;
    return c.f;
}
__device__ __forceinline__ void split_bf16(const float (&v)[8], bf16x8& hi, bf16x8& lo) {
    unsigned uh[4], ul[4];
    #pragma unroll
    for (int i = 0; i < 4; ++i) {
        unsigned short h0 = f2bf(v[2*i]),   h1 = f2bf(v[2*i+1]);
        float r0 = v[2*i] - bf2f(h0),       r1 = v[2*i+1] - bf2f(h1);
        unsigned short l0 = f2bf(r0),       l1 = f2bf(r1);
        uh[i] = (unsigned)h0 | ((unsigned)h1 << 16);
        ul[i] = (unsigned)l0 | ((unsigned)l1 << 16);
    }
    FragCast ch, cl;
    ch.u.x = uh[0]; ch.u.y = uh[1]; ch.u.z = uh[2]; ch.u.w = uh[3];
    cl.u.x = ul[0]; cl.u.y = ul[1]; cl.u.z = ul[2]; cl.u.w = ul[3];
    hi = ch.v; lo = cl.v;
}

// ---------- init + CSR count + iteration-0 xg ----------
// xg layout: [link][32][4] = {z, r, n, pad} per state-col, biases folded in.
__global__ __launch_bounds__(256) void init_kernel(
    const int*   __restrict__ links,
    const float* __restrict__ cap, const float* __restrict__ pol, const float* __restrict__ wts,
    const float* __restrict__ bw,  const float* __restrict__ tos,
    const float* __restrict__ pk,  const float* __restrict__ avg,
    const float* __restrict__ Wp,  const float* __restrict__ bp,
    float* __restrict__ link_state, float* __restrict__ path_state,
    float* __restrict__ xg,
    int* __restrict__ cnt)
{
    int i = blockIdx.x * 256 + threadIdx.x;
    if (i < E_TOT) atomicAdd(&cnt[links[i]], 1);
    if (i < NLINKS) {
        float row[DIM];
        #pragma unroll
        for (int c = 0; c < DIM; ++c) row[c] = 0.0f;
        row[0] = cap[i]; row[1] = pol[i]; row[2] = wts[i];
        float4* o = (float4*)(link_state + (size_t)i * DIM);
        #pragma unroll
        for (int c = 0; c < 8; ++c) {
            float4 v = { row[4*c], row[4*c+1], row[4*c+2], row[4*c+3] };
            o[c] = v;
        }
        // xg0 = ls0 @ Wp + folded biases; ls0 has only dims 0..2 nonzero.
        float a = row[0], b = row[1], c3 = row[2];
        float4* xo = (float4*)(xg + (size_t)i * 128);
        #pragma unroll 4
        for (int c = 0; c < 32; ++c) {
            float z = a * Wp[c]      + b * Wp[96+c]  + c3 * Wp[192+c] + bp[c]    + bp[96+c];
            float r = a * Wp[32+c]   + b * Wp[128+c] + c3 * Wp[224+c] + bp[32+c] + bp[128+c];
            float n = a * Wp[64+c]   + b * Wp[160+c] + c3 * Wp[256+c] + bp[64+c];
            float4 v = { z, r, n, 0.0f };
            xo[c] = v;
        }
    }
    if (i < NP) {
        float row[DIM];
        #pragma unroll
        for (int c = 0; c < DIM; ++c) row[c] = 0.0f;
        row[0] = bw[i]; row[1] = tos[i]; row[2] = pk[i]; row[3] = avg[i];
        float4* o = (float4*)(path_state + (size_t)i * DIM);
        #pragma unroll
        for (int c = 0; c < 8; ++c) {
            float4 v = { row[4*c], row[4*c+1], row[4*c+2], row[4*c+3] };
            o[c] = v;
        }
    }
}

// ---------- prep item helpers ----------
__device__ __forceinline__ void wprep_item(const float* __restrict__ W,
                                           const float* __restrict__ U,
                                           unsigned short* __restrict__ ofr, int idx)
{
    int j = idx & 7, lane = (idx >> 3) & 63, g = idx >> 9;
    int k = (lane >> 4) * 8 + j;
    int n = g * 16 + (lane & 15);
    float w = W[k * 96 + n];
    float u = U[k * 96 + n];
    unsigned short whi = f2bf(w); unsigned short wlo = f2bf(w - bf2f(whi));
    unsigned short uhi = f2bf(u); unsigned short ulo = f2bf(u - bf2f(uhi));
    ofr[0 * 3072 + idx] = whi;
    ofr[1 * 3072 + idx] = wlo;
    ofr[2 * 3072 + idx] = uhi;
    ofr[3 * 3072 + idx] = ulo;
}

__device__ __forceinline__ void rprep_item(const float* __restrict__ R1,
                                           const float* __restrict__ R2,
                                           unsigned short* __restrict__ rfr, int idx)
{
    if (idx < 8192) {
        int j = idx & 7, lane = (idx >> 3) & 63, g = idx >> 9;
        int k = (lane >> 4) * 8 + j;
        int n = g * 16 + (lane & 15);
        float v = R1[k * 256 + n];
        unsigned short hi = f2bf(v);
        rfr[idx] = hi;
        rfr[8192 + idx] = f2bf(v - bf2f(hi));
    } else {
        int idx2 = idx - 8192;
        int j = idx2 & 7, lane = (idx2 >> 3) & 63, tile = idx2 >> 9;
        int c = tile >> 4, g = tile & 15;
        int k = c * 32 + (lane >> 4) * 8 + j;
        int n = g * 16 + (lane & 15);
        float v = R2[k * 256 + n];
        unsigned short hi = f2bf(v);
        rfr[16384 + idx2] = hi;
        rfr[16384 + 65536 + idx2] = f2bf(v - bf2f(hi));
    }
}

// ---------- merged prep: block 0 = CSR scan; blocks 1.. = weight frag prep ----
__global__ __launch_bounds__(256) void prep_kernel(
    const int*   __restrict__ cnt,
    int* __restrict__ row_start, int* __restrict__ cursor,
    const float* __restrict__ Wp, const float* __restrict__ Up,
    unsigned short* __restrict__ wfr,
    const float* __restrict__ Wl, const float* __restrict__ Ul,
    unsigned short* __restrict__ lfr,
    const float* __restrict__ R1, const float* __restrict__ R2,
    unsigned short* __restrict__ rfr)
{
    int t = threadIdx.x;
    if (blockIdx.x == 0) {
        __shared__ int s[256];
        const int CH = (NLINKS + 255) / 256;   // 40
        int base = t * CH;
        int sum = 0;
        for (int i = 0; i < CH; ++i) {
            int idx = base + i;
            if (idx < NLINKS) sum += cnt[idx];
        }
        s[t] = sum;
        __syncthreads();
        for (int off = 1; off < 256; off <<= 1) {
            int v = (t >= off) ? s[t - off] : 0;
            __syncthreads();
            s[t] += v;
            __syncthreads();
        }
        int run = s[t] - sum;
        for (int i = 0; i < CH; ++i) {
            int idx = base + i;
            if (idx < NLINKS) {
                row_start[idx] = run;
                cursor[idx]    = run;
                run += cnt[idx];
            }
        }
        if (t == 255) row_start[NLINKS] = s[255];
        return;
    }
    int idx = (blockIdx.x - 1) * 256 + t;
    if (idx < 3072) {
        wprep_item(Wp, Up, wfr, idx);
    } else if (idx < 6144) {
        wprep_item(Wl, Ul, lfr, idx - 3072);
    } else if (idx < 6144 + 8192 + 65536) {
        rprep_item(R1, R2, rfr, idx - 6144);
    }
}

__global__ __launch_bounds__(256) void csr_scatter(const int* __restrict__ links,
                                                   int* __restrict__ cursor,
                                                   int* __restrict__ slot)
{
    int e = blockIdx.x * 256 + threadIdx.x;
    if (e < E_TOT) slot[e] = atomicAdd(&cursor[links[e]], 1);
}

// ---------- shared device body: 5-hop MFMA path GRU for one 16-path tile ----
// LDS transposes rely on same-wave DS in-order processing: ds_write then
// ds_read from the SAME wave needs no intermediate drain; only the post-read
// data wait (lgkmcnt 0) before register use.
template <bool STORE_M>
__device__ __forceinline__ void path_gru_body(
    int p0, int l15, int quad, float* T,
    const int* __restrict__ links,
    const float* __restrict__ xg,
    const unsigned short* __restrict__ wfr,
    const float* __restrict__ bp,
    const int* __restrict__ slot,
    const float* __restrict__ path_state,
    float* __restrict__ m,
    float (&hA)[8])
{
    int lane = quad * 16 + l15;
    int p = p0 + l15;
    int sl[PLEN];
    if (STORE_M) {
        #pragma unroll
        for (int l = 0; l < PLEN; ++l) sl[l] = slot[p * PLEN + l];
    }

    // link ids for the 4 acc-row paths, all hops (feeds the xv gathers)
    int lk[PLEN][4];
    #pragma unroll
    for (int rg = 0; rg < 4; ++rg) {
        int pb = (p0 + quad * 4 + rg) * PLEN;
        #pragma unroll
        for (int l = 0; l < PLEN; ++l) lk[l][rg] = links[pb + l];
    }

    // U fragments only (hi/lo)
    bf16x8 Uh[6], Ul[6];
    {
        const uint4* base = (const uint4*)wfr;
        #pragma unroll
        for (int g = 0; g < 6; ++g) {
            FragCast a;
            a.u = base[2 * 384 + g * 64 + lane]; Uh[g] = a.v;
            a.u = base[3 * 384 + g * 64 + lane]; Ul[g] = a.v;
        }
    }
    float bnh[2];
    #pragma unroll
    for (int hf = 0; hf < 2; ++hf) bnh[hf] = bp[96 + 64 + hf * 16 + l15];

    {
        const float4* src = (const float4*)(path_state + (size_t)p * DIM + quad * 8);
        float4 v0 = src[0], v1 = src[1];
        hA[0]=v0.x; hA[1]=v0.y; hA[2]=v0.z; hA[3]=v0.w;
        hA[4]=v1.x; hA[5]=v1.y; hA[6]=v1.z; hA[7]=v1.w;
    }
    #pragma unroll
    for (int j = 0; j < 8; ++j) T[l15 * 36 + quad * 8 + j] = hA[j];
    float hC[2][4];
    #pragma unroll
    for (int hf = 0; hf < 2; ++hf)
        #pragma unroll
        for (int rg = 0; rg < 4; ++rg)
            hC[hf][rg] = T[(quad * 4 + rg) * 36 + hf * 16 + l15];
    __asm__ volatile("s_waitcnt lgkmcnt(0)" ::: "memory");

    bf16x8 ah, al;
    split_bf16(hA, ah, al);

    #pragma unroll
    for (int l = 0; l < PLEN; ++l) {
        // gather precomputed gate pre-activations for the 4 acc-row paths
        float4 xv[2][4];
        #pragma unroll
        for (int rg = 0; rg < 4; ++rg) {
            const float4* xp = (const float4*)(xg + (size_t)lk[l][rg] * 128);
            xv[0][rg] = xp[l15];
            xv[1][rg] = xp[16 + l15];
        }
        #pragma unroll
        for (int hf = 0; hf < 2; ++hf) {
            f32x4 az  = { xv[hf][0].x, xv[hf][1].x, xv[hf][2].x, xv[hf][3].x };
            f32x4 ar  = { xv[hf][0].y, xv[hf][1].y, xv[hf][2].y, xv[hf][3].y };
            f32x4 ahg = { 0.f, 0.f, 0.f, 0.f };
            int gz = hf, gr = 2 + hf, gn = 4 + hf;
            az  = __builtin_amdgcn_mfma_f32_16x16x32_bf16(ah, Uh[gz], az,  0, 0, 0);
            ar  = __builtin_amdgcn_mfma_f32_16x16x32_bf16(ah, Uh[gr], ar,  0, 0, 0);
            ahg = __builtin_amdgcn_mfma_f32_16x16x32_bf16(ah, Uh[gn], ahg, 0, 0, 0);
            az  = __builtin_amdgcn_mfma_f32_16x16x32_bf16(ah, Ul[gz], az,  0, 0, 0);
            ar  = __builtin_amdgcn_mfma_f32_16x16x32_bf16(ah, Ul[gr], ar,  0, 0, 0);
            ahg = __builtin_amdgcn_mfma_f32_16x16x32_bf16(ah, Ul[gn], ahg, 0, 0, 0);
            az  = __builtin_amdgcn_mfma_f32_16x16x32_bf16(al, Uh[gz], az,  0, 0, 0);
            ar  = __builtin_amdgcn_mfma_f32_16x16x32_bf16(al, Uh[gr], ar,  0, 0, 0);
            ahg = __builtin_amdgcn_mfma_f32_16x16x32_bf16(al, Uh[gn], ahg, 0, 0, 0);
            #pragma unroll
            for (int rg = 0; rg < 4; ++rg) {
                float z  = fast_sigmoid(az[rg]);
                float r  = fast_sigmoid(ar[rg]);
                float hn = fast_tanh(xv[hf][rg].z + r * (ahg[rg] + bnh[hf]));
                hC[hf][rg] = z * hC[hf][rg] + (1.0f - z) * hn;
            }
        }

        // same-wave transpose: write then read, single post-read drain
        #pragma unroll
        for (int hf = 0; hf < 2; ++hf)
            #pragma unroll
            for (int rg = 0; rg < 4; ++rg)
                T[(quad * 4 + rg) * 36 + hf * 16 + l15] = hC[hf][rg];
        {
            const float4* rd = (const float4*)(T + l15 * 36 + quad * 8);
            float4 v0 = rd[0], v1 = rd[1];
            __asm__ volatile("s_waitcnt lgkmcnt(0)" ::: "memory");
            hA[0]=v0.x; hA[1]=v0.y; hA[2]=v0.z; hA[3]=v0.w;
            hA[4]=v1.x; hA[5]=v1.y; hA[6]=v1.z; hA[7]=v1.w;
        }
        if (STORE_M) {
            float4* dst = (float4*)(m + (size_t)sl[l] * DIM + quad * 8);
            float4 v0 = { hA[0], hA[1], hA[2], hA[3] };
            float4 v1 = { hA[4], hA[5], hA[6], hA[7] };
            dst[0] = v0; dst[1] = v1;
        }
        if (l < PLEN - 1) split_bf16(hA, ah, al);
    }
}

// ---------- MFMA path GRU kernel (iterations 0..6) ----------
__global__ __launch_bounds__(256) void path_kernel(
    const int*   __restrict__ links,
    const float* __restrict__ xg,
    const unsigned short* __restrict__ wfr,
    const float* __restrict__ bp,
    const int*   __restrict__ slot,
    float* __restrict__ path_state,
    float* __restrict__ m)
{
    __shared__ __align__(16) float T4[4][16 * 36];
    int t = threadIdx.x;
    int wave = t >> 6, lane = t & 63;
    int l15 = lane & 15, quad = lane >> 4;
    int p0 = (blockIdx.x * 4 + wave) * 16;
    if (p0 >= NP) return;
    int p = p0 + l15;
    float hA[8];
    path_gru_body<true>(p0, l15, quad, T4[wave], links, xg, wfr, bp,
                        slot, path_state, m, hA);
    float4* ho = (float4*)(path_state + (size_t)p * DIM + quad * 8);
    float4 v0 = { hA[0], hA[1], hA[2], hA[3] };
    float4 v1 = { hA[4], hA[5], hA[6], hA[7] };
    ho[0] = v0; ho[1] = v1;
}

// ---------- segment-sum: one wave per link, coalesced CSR-ordered read ----
// 2-way unrolled (two accumulator sets) for more loads in flight.
__global__ __launch_bounds__(256) void agg_kernel(
    const int* __restrict__ row_start,
    const float* __restrict__ m,
    float* __restrict__ x_sum)
{
    int t = threadIdx.x;
    int wave = t >> 6, lane = t & 63;
    int link = blockIdx.x * 4 + wave;
    if (link >= NLINKS) return;
    int r = lane >> 3;
    int c = lane & 7;
    int s0 = row_start[link], s1 = row_start[link + 1];
    float4 a0 = {0.f, 0.f, 0.f, 0.f};
    float4 a1 = {0.f, 0.f, 0.f, 0.f};
    int i = s0 + r;
    for (; i + 8 < s1; i += 16) {
        const float4 v0 = *(const float4*)(m + (size_t)i * DIM + c * 4);
        const float4 v1 = *(const float4*)(m + (size_t)(i + 8) * DIM + c * 4);
        a0.x += v0.x; a0.y += v0.y; a0.z += v0.z; a0.w += v0.w;
        a1.x += v1.x; a1.y += v1.y; a1.z += v1.z; a1.w += v1.w;
    }
    for (; i < s1; i += 8) {
        const float4 v = *(const float4*)(m + (size_t)i * DIM + c * 4);
        a0.x += v.x; a0.y += v.y; a0.z += v.z; a0.w += v.w;
    }
    float4 acc = { a0.x + a1.x, a0.y + a1.y, a0.z + a1.z, a0.w + a1.w };
    #pragma unroll
    for (int off = 8; off < 64; off <<= 1) {
        acc.x += __shfl_xor(acc.x, off);
        acc.y += __shfl_xor(acc.y, off);
        acc.z += __shfl_xor(acc.z, off);
        acc.w += __shfl_xor(acc.w, off);
    }
    if (r == 0)
        *(float4*)(x_sum + (size_t)link * DIM + c * 4) = acc;
}

// ---------- link GRU: one wave per 16-link tile (full-chip distribution) ----
__global__ __launch_bounds__(64) void aglk_kernel(
    const float* __restrict__ x_sum,
    const unsigned short* __restrict__ lfr,
    const float* __restrict__ bl,
    const unsigned short* __restrict__ wfr,
    const float* __restrict__ bp,
    float* __restrict__ link_state,
    float* __restrict__ xg)
{
    __shared__ __align__(16) float T[16 * 36];
    int lane = threadIdx.x;
    int l15 = lane & 15, quad = lane >> 4;
    int lb = blockIdx.x * 16;
    if (lb >= NLINKS) return;
    int link = lb + l15;

    bf16x8 Wh[6], Wlo[6], Uh[6], Ulo[6];
    {
        const uint4* base = (const uint4*)lfr;
        #pragma unroll
        for (int g = 0; g < 6; ++g) {
            FragCast a;
            a.u = base[0 * 384 + g * 64 + lane]; Wh[g]  = a.v;
            a.u = base[1 * 384 + g * 64 + lane]; Wlo[g] = a.v;
            a.u = base[2 * 384 + g * 64 + lane]; Uh[g]  = a.v;
            a.u = base[3 * 384 + g * 64 + lane]; Ulo[g] = a.v;
        }
    }
    float bz[2], br[2], bnx[2], bnh[2];
    #pragma unroll
    for (int hf = 0; hf < 2; ++hf) {
        int c = hf * 16 + l15;
        bz[hf]  = bl[c]      + bl[96 + c];
        br[hf]  = bl[32 + c] + bl[96 + 32 + c];
        bnx[hf] = bl[64 + c];
        bnh[hf] = bl[96 + 64 + c];
    }

    float x8[8];
    {
        const float4* xs = (const float4*)(x_sum + (size_t)link * DIM + quad * 8);
        float4 a = xs[0], b = xs[1];
        x8[0]=a.x; x8[1]=a.y; x8[2]=a.z; x8[3]=a.w;
        x8[4]=b.x; x8[5]=b.y; x8[6]=b.z; x8[7]=b.w;
    }
    bf16x8 xh, xl;
    split_bf16(x8, xh, xl);

    float hA[8];
    {
        const float4* src = (const float4*)(link_state + (size_t)link * DIM + quad * 8);
        float4 v0 = src[0], v1 = src[1];
        hA[0]=v0.x; hA[1]=v0.y; hA[2]=v0.z; hA[3]=v0.w;
        hA[4]=v1.x; hA[5]=v1.y; hA[6]=v1.z; hA[7]=v1.w;
    }
    #pragma unroll
    for (int j = 0; j < 8; ++j) T[l15 * 36 + quad * 8 + j] = hA[j];
    float hC[2][4];
    #pragma unroll
    for (int hf = 0; hf < 2; ++hf)
        #pragma unroll
        for (int rg = 0; rg < 4; ++rg)
            hC[hf][rg] = T[(quad * 4 + rg) * 36 + hf * 16 + l15];
    __asm__ volatile("s_waitcnt lgkmcnt(0)" ::: "memory");
    bf16x8 ah, al;
    split_bf16(hA, ah, al);

    #pragma unroll
    for (int hf = 0; hf < 2; ++hf) {
        f32x4 az = {0.f,0.f,0.f,0.f}, ar = {0.f,0.f,0.f,0.f};
        f32x4 axn = {0.f,0.f,0.f,0.f}, ahg = {0.f,0.f,0.f,0.f};
        int gz = hf, gr = 2 + hf, gn = 4 + hf;
        az = __builtin_amdgcn_mfma_f32_16x16x32_bf16(xh, Wh[gz],  az, 0, 0, 0);
        az = __builtin_amdgcn_mfma_f32_16x16x32_bf16(xh, Wlo[gz], az, 0, 0, 0);
        az = __builtin_amdgcn_mfma_f32_16x16x32_bf16(xl, Wh[gz],  az, 0, 0, 0);
        az = __builtin_amdgcn_mfma_f32_16x16x32_bf16(ah, Uh[gz],  az, 0, 0, 0);
        az = __builtin_amdgcn_mfma_f32_16x16x32_bf16(ah, Ulo[gz], az, 0, 0, 0);
        az = __builtin_amdgcn_mfma_f32_16x16x32_bf16(al, Uh[gz],  az, 0, 0, 0);
        ar = __builtin_amdgcn_mfma_f32_16x16x32_bf16(xh, Wh[gr],  ar, 0, 0, 0);
        ar = __builtin_amdgcn_mfma_f32_16x16x32_bf16(xh, Wlo[gr], ar, 0, 0, 0);
        ar = __builtin_amdgcn_mfma_f32_16x16x32_bf16(xl, Wh[gr],  ar, 0, 0, 0);
        ar = __builtin_amdgcn_mfma_f32_16x16x32_bf16(ah, Uh[gr],  ar, 0, 0, 0);
        ar = __builtin_amdgcn_mfma_f32_16x16x32_bf16(ah, Ulo[gr], ar, 0, 0, 0);
        ar = __builtin_amdgcn_mfma_f32_16x16x32_bf16(al, Uh[gr],  ar, 0, 0, 0);
        axn = __builtin_amdgcn_mfma_f32_16x16x32_bf16(xh, Wh[gn],  axn, 0, 0, 0);
        axn = __builtin_amdgcn_mfma_f32_16x16x32_bf16(xh, Wlo[gn], axn, 0, 0, 0);
        axn = __builtin_amdgcn_mfma_f32_16x16x32_bf16(xl, Wh[gn],  axn, 0, 0, 0);
        ahg = __builtin_amdgcn_mfma_f32_16x16x32_bf16(ah, Uh[gn],  ahg, 0, 0, 0);
        ahg = __builtin_amdgcn_mfma_f32_16x16x32_bf16(ah, Ulo[gn], ahg, 0, 0, 0);
        ahg = __builtin_amdgcn_mfma_f32_16x16x32_bf16(al, Uh[gn],  ahg, 0, 0, 0);
        #pragma unroll
        for (int rg = 0; rg < 4; ++rg) {
            float z  = fast_sigmoid(az[rg] + bz[hf]);
            float r  = fast_sigmoid(ar[rg] + br[hf]);
            float hn = fast_tanh(axn[rg] + bnx[hf] + r * (ahg[rg] + bnh[hf]));
            hC[hf][rg] = z * hC[hf][rg] + (1.0f - z) * hn;
        }
    }

    #pragma unroll
    for (int hf = 0; hf < 2; ++hf)
        #pragma unroll
        for (int rg = 0; rg < 4; ++rg)
            T[(quad * 4 + rg) * 36 + hf * 16 + l15] = hC[hf][rg];
    {
        const float4* rd = (const float4*)(T + l15 * 36 + quad * 8);
        float4 v0 = rd[0], v1 = rd[1];
        __asm__ volatile("s_waitcnt lgkmcnt(0)" ::: "memory");
        hA[0]=v0.x; hA[1]=v0.y; hA[2]=v0.z; hA[3]=v0.w;
        hA[4]=v1.x; hA[5]=v1.y; hA[6]=v1.z; hA[7]=v1.w;
    }
    float4* ho = (float4*)(link_state + (size_t)link * DIM + quad * 8);
    float4 v0 = { hA[0], hA[1], hA[2], hA[3] };
    float4 v1 = { hA[4], hA[5], hA[6], hA[7] };
    ho[0] = v0; ho[1] = v1;

    // ---- xg for next path iteration: new_h @ Wp + folded path biases ----
    bf16x8 nh, nl;
    split_bf16(hA, nh, nl);
    {
        const uint4* wb = (const uint4*)wfr;
        #pragma unroll
        for (int hf2 = 0; hf2 < 2; ++hf2) {
            int c0 = hf2 * 16 + l15;
            float foldz = bp[c0]      + bp[96 + c0];
            float foldr = bp[32 + c0] + bp[128 + c0];
            float foldn = bp[64 + c0];
            FragCast wzh, wzl, wrh, wrl, wnh, wnl;
            wzh.u = wb[0 * 384 + (hf2)     * 64 + lane];
            wzl.u = wb[1 * 384 + (hf2)     * 64 + lane];
            wrh.u = wb[0 * 384 + (2 + hf2) * 64 + lane];
            wrl.u = wb[1 * 384 + (2 + hf2) * 64 + lane];
            wnh.u = wb[0 * 384 + (4 + hf2) * 64 + lane];
            wnl.u = wb[1 * 384 + (4 + hf2) * 64 + lane];
            f32x4 cz = {0.f,0.f,0.f,0.f}, cr = {0.f,0.f,0.f,0.f}, cn = {0.f,0.f,0.f,0.f};
            cz = __builtin_amdgcn_mfma_f32_16x16x32_bf16(nh, wzh.v, cz, 0, 0, 0);
            cr = __builtin_amdgcn_mfma_f32_16x16x32_bf16(nh, wrh.v, cr, 0, 0, 0);
            cn = __builtin_amdgcn_mfma_f32_16x16x32_bf16(nh, wnh.v, cn, 0, 0, 0);
            cz = __builtin_amdgcn_mfma_f32_16x16x32_bf16(nh, wzl.v, cz, 0, 0, 0);
            cr = __builtin_amdgcn_mfma_f32_16x16x32_bf16(nh, wrl.v, cr, 0, 0, 0);
            cn = __builtin_amdgcn_mfma_f32_16x16x32_bf16(nh, wnl.v, cn, 0, 0, 0);
            cz = __builtin_amdgcn_mfma_f32_16x16x32_bf16(nl, wzh.v, cz, 0, 0, 0);
            cr = __builtin_amdgcn_mfma_f32_16x16x32_bf16(nl, wrh.v, cr, 0, 0, 0);
            cn = __builtin_amdgcn_mfma_f32_16x16x32_bf16(nl, wnh.v, cn, 0, 0, 0);
            #pragma unroll
            for (int rg = 0; rg < 4; ++rg) {
                float4 v = { cz[rg] + foldz, cr[rg] + foldr, cn[rg] + foldn, 0.f };
                *(float4*)(xg + (size_t)(lb + quad * 4 + rg) * 128 + c0 * 4) = v;
            }
        }
    }
}

// ---------- fused: final path GRU iteration + MFMA readout ----------
// Readout uses swapped-operand chaining: h0 (B-layout from GRU) -> R1 as
// mfma(R1^T-frag, h0) -> quad-butterfly (2 shfl_xor) into B-frags of h1 ->
// R2 as mfma(R2^T-frag, h1) -> per-lane dot with R3, quad reduce.
__global__ __launch_bounds__(128, 1) void readout_kernel(
    const int*   __restrict__ links,
    const float* __restrict__ xg,
    const unsigned short* __restrict__ wfr,
    const float* __restrict__ bp,
    const float* __restrict__ path_state,
    const unsigned short* __restrict__ rfr,
    const float* __restrict__ Rb1, const float* __restrict__ Rb2,
    const float* __restrict__ R3,  const float* __restrict__ Rb3,
    float* __restrict__ out)
{
    __shared__ __align__(16) float T2[2][16 * 36];
    int t = threadIdx.x;
    int wave = t >> 6, lane = t & 63;
    int l15 = lane & 15, quad = lane >> 4;
    int p0 = (blockIdx.x * 2 + wave) * 16;
    if (p0 >= NP) return;
    float* T = T2[wave];

    float h0[8];
    path_gru_body<false>(p0, l15, quad, T, links, xg, wfr, bp,
                         nullptr, path_state, nullptr, h0);

    const uint4* r1h = (const uint4*)rfr;
    const uint4* r1l = r1h + 1024;
    const uint4* r2h = r1l + 1024;
    const uint4* r2l = r2h + 8192;

    // h0 is already a B fragment (k=dim chunk quad, n=path l15)
    bf16x8 b0h, b0l;
    split_bf16(h0, b0h, b0l);

    // R1 swapped: per c-chunk, chains g=2c (even) and 2c+1 (odd); exchange
    // outputs across quads into B-fragments bh/bl[c] of h1 (k-dims c*32..+31).
    bf16x8 bh[8], bl[8];
    #pragma unroll
    for (int c = 0; c < 8; ++c) {
        FragCast feh, fel, foh, fol;
        feh.u = r1h[(2*c)   * 64 + lane]; fel.u = r1l[(2*c)   * 64 + lane];
        foh.u = r1h[(2*c+1) * 64 + lane]; fol.u = r1l[(2*c+1) * 64 + lane];
        f32x4 ce = {0.f,0.f,0.f,0.f}, co = {0.f,0.f,0.f,0.f};
        ce = __builtin_amdgcn_mfma_f32_16x16x32_bf16(feh.v, b0h, ce, 0, 0, 0);
        co = __builtin_amdgcn_mfma_f32_16x16x32_bf16(foh.v, b0h, co, 0, 0, 0);
        ce = __builtin_amdgcn_mfma_f32_16x16x32_bf16(feh.v, b0l, ce, 0, 0, 0);
        co = __builtin_amdgcn_mfma_f32_16x16x32_bf16(foh.v, b0l, co, 0, 0, 0);
        ce = __builtin_amdgcn_mfma_f32_16x16x32_bf16(fel.v, b0h, ce, 0, 0, 0);
        co = __builtin_amdgcn_mfma_f32_16x16x32_bf16(fol.v, b0h, co, 0, 0, 0);
        float rbe[4], rbo[4];
        {
            float4 v0 = *(const float4*)(Rb1 + c * 32 + quad * 4);
            float4 v1 = *(const float4*)(Rb1 + c * 32 + 16 + quad * 4);
            rbe[0]=v0.x; rbe[1]=v0.y; rbe[2]=v0.z; rbe[3]=v0.w;
            rbo[0]=v1.x; rbo[1]=v1.y; rbo[2]=v1.z; rbo[3]=v1.w;
        }
        float o8[8];
        #pragma unroll
        for (int rg = 0; rg < 4; ++rg) {
            float e = seluf(ce[rg] + rbe[rg]);   // h1[c*32 + quad*4 + rg]
            float o = seluf(co[rg] + rbo[rg]);   // h1[c*32 + 16 + quad*4 + rg]
            float s1 = (quad < 2) ? o : e;
            float r1v = __shfl_xor(s1, 32);
            float x = (quad < 2) ? e : r1v;
            float y = (quad < 2) ? r1v : o;
            float s2 = ((quad & 1) == 0) ? y : x;
            float r2v = __shfl_xor(s2, 16);
            o8[rg]     = ((quad & 1) == 0) ? x : r2v;  // h1[c*32+quad*8+rg]
            o8[4 + rg] = ((quad & 1) == 0) ? r2v : y;  // h1[c*32+quad*8+4+rg]
        }
        split_bf16(o8, bh[c], bl[c]);
    }

    // R2 swapped: 4 concurrent chains over out-dim groups g; A-frags streamed
    // from rfr, B = bh/bl registers. s = per-lane (path l15) partial dot.
    float s = 0.f;
    #pragma unroll 1
    for (int g = 0; g < 16; g += 4) {
        f32x4 a0 = {0.f,0.f,0.f,0.f}, a1 = {0.f,0.f,0.f,0.f};
        f32x4 a2 = {0.f,0.f,0.f,0.f}, a3 = {0.f,0.f,0.f,0.f};
        #pragma unroll
        for (int c = 0; c < 8; ++c) {
            FragCast f0h, f0l, f1h, f1l, f2h, f2l, f3h, f3l;
            f0h.u = r2h[(c * 16 + g + 0) * 64 + lane];
            f0l.u = r2l[(c * 16 + g + 0) * 64 + lane];
            f1h.u = r2h[(c * 16 + g + 1) * 64 + lane];
            f1l.u = r2l[(c * 16 + g + 1) * 64 + lane];
            f2h.u = r2h[(c * 16 + g + 2) * 64 + lane];
            f2l.u = r2l[(c * 16 + g + 2) * 64 + lane];
            f3h.u = r2h[(c * 16 + g + 3) * 64 + lane];
            f3l.u = r2l[(c * 16 + g + 3) * 64 + lane];
            a0 = __builtin_amdgcn_mfma_f32_16x16x32_bf16(f0h.v, bh[c], a0, 0, 0, 0);
            a1 = __builtin_amdgcn_mfma_f32_16x16x32_bf16(f1h.v, bh[c], a1, 0, 0, 0);
            a2 = __builtin_amdgcn_mfma_f32_16x16x32_bf16(f2h.v, bh[c], a2, 0, 0, 0);
            a3 = __builtin_amdgcn_mfma_f32_16x16x32_bf16(f3h.v, bh[c], a3, 0, 0, 0);
            a0 = __builtin_amdgcn_mfma_f32_16x16x32_bf16(f0l.v, bh[c], a0, 0, 0, 0);
            a1 = __builtin_amdgcn_mfma_f32_16x16x32_bf16(f1l.v, bh[c], a1, 0, 0, 0);
            a2 = __builtin_amdgcn_mfma_f32_16x16x32_bf16(f2l.v, bh[c], a2, 0, 0, 0);
            a3 = __builtin_amdgcn_mfma_f32_16x16x32_bf16(f3l.v, bh[c], a3, 0, 0, 0);
            a0 = __builtin_amdgcn_mfma_f32_16x16x32_bf16(f0h.v, bl[c], a0, 0, 0, 0);
            a1 = __builtin_amdgcn_mfma_f32_16x16x32_bf16(f1h.v, bl[c], a1, 0, 0, 0);
            a2 = __builtin_amdgcn_mfma_f32_16x16x32_bf16(f2h.v, bl[c], a2, 0, 0, 0);
            a3 = __builtin_amdgcn_mfma_f32_16x16x32_bf16(f3h.v, bl[c], a3, 0, 0, 0);
        }
        #pragma unroll
        for (int u = 0; u < 4; ++u) {
            f32x4 aa = (u == 0) ? a0 : (u == 1) ? a1 : (u == 2) ? a2 : a3;
            float rb2[4], r3v[4];
            {
                float4 vb = *(const float4*)(Rb2 + (g + u) * 16 + quad * 4);
                float4 vr = *(const float4*)(R3  + (g + u) * 16 + quad * 4);
                rb2[0]=vb.x; rb2[1]=vb.y; rb2[2]=vb.z; rb2[3]=vb.w;
                r3v[0]=vr.x; r3v[1]=vr.y; r3v[2]=vr.z; r3v[3]=vr.w;
            }
            #pragma unroll
            for (int rg = 0; rg < 4; ++rg)
                s += seluf(aa[rg] + rb2[rg]) * r3v[rg];
        }
    }
    // reduce partial dots across the 4 quads (same path l15)
    s += __shfl_xor(s, 16);
    s += __shfl_xor(s, 32);
    if (quad == 0)
        out[p0 + l15] = s + Rb3[0];
}

extern "C" void kernel_launch(void* const* d_in, const int* in_sizes, int n_in,
                              void* d_out, int out_size, void* d_ws, size_t ws_size,
                              hipStream_t stream)
{
    const int*   links = (const int*)d_in[0];
    const float* cap = (const float*)d_in[3];
    const float* pol = (const float*)d_in[4];
    const float* wts = (const float*)d_in[5];
    const float* bw  = (const float*)d_in[6];
    const float* tos = (const float*)d_in[7];
    const float* pk  = (const float*)d_in[8];
    const float* avg = (const float*)d_in[9];
    const float* Wp  = (const float*)d_in[10];
    const float* Up  = (const float*)d_in[11];
    const float* bp  = (const float*)d_in[12];
    const float* Wl  = (const float*)d_in[13];
    const float* Ul  = (const float*)d_in[14];
    const float* bl  = (const float*)d_in[15];
    const float* R1  = (const float*)d_in[16];
    const float* Rb1 = (const float*)d_in[17];
    const float* R2  = (const float*)d_in[18];
    const float* Rb2 = (const float*)d_in[19];
    const float* R3  = (const float*)d_in[20];
    const float* Rb3 = (const float*)d_in[21];

    char* w = (char*)d_ws;
    size_t off = 0;
    auto alloc = [&](size_t bytes) {
        char* p = w + off;
        off += (bytes + 255) & ~(size_t)255;
        return p;
    };
    float*          path_state = (float*)alloc((size_t)NP * DIM * 4);
    float*          link_state = (float*)alloc((size_t)NLINKS * DIM * 4);
    float*          m          = (float*)alloc((size_t)E_TOT * DIM * 4);
    float*          xg         = (float*)alloc((size_t)NLINKS * 128 * 4);
    float*          x_sum      = (float*)alloc((size_t)NLINKS * DIM * 4);
    unsigned short* wfr        = (unsigned short*)alloc(4 * 3072 * 2);
    unsigned short* lfr        = (unsigned short*)alloc(4 * 3072 * 2);
    unsigned short* rfr        = (unsigned short*)alloc((size_t)(8192 + 65536) * 2 * 2);
    int*            cnt        = (int*)alloc((size_t)NLINKS * 4);
    int*            row_start  = (int*)alloc((size_t)(NLINKS + 1) * 4);
    int*            cursor     = (int*)alloc((size_t)NLINKS * 4);
    int*            slot       = (int*)alloc((size_t)E_TOT * 4);

    hipMemsetAsync(cnt, 0, (size_t)NLINKS * 4, stream);
    init_kernel<<<(E_TOT + 255) / 256, 256, 0, stream>>>(links, cap, pol, wts, bw, tos,
                                                         pk, avg, Wp, bp,
                                                         link_state, path_state, xg, cnt);
    prep_kernel<<<1 + 12 + 12 + 288, 256, 0, stream>>>(cnt, row_start, cursor,
                                                       Wp, Up, wfr, Wl, Ul, lfr,
                                                       R1, R2, rfr);
    csr_scatter<<<(E_TOT + 255) / 256, 256, 0, stream>>>(links, cursor, slot);

    const int PGRID = (NP / 16 + 3) / 4;
    const int AGRID = (NLINKS + 3) / 4;
    const int LGRID = NLINKS / 16;   // one 16-link tile per 64-thread block
    for (int it = 0; it < TITERS - 1; ++it) {
        path_kernel<<<PGRID, 256, 0, stream>>>(links, xg, wfr, bp,
                                               slot, path_state, m);
        agg_kernel<<<AGRID, 256, 0, stream>>>(row_start, m, x_sum);
        aglk_kernel<<<LGRID, 64, 0, stream>>>(x_sum, lfr, bl, wfr, bp,
                                              link_state, xg);
    }
    readout_kernel<<<(NP / 16 + 1) / 2, 128, 0, stream>>>(links, xg, wfr, bp,
                                                          path_state, rfr, Rb1, Rb2,
                                                          R3, Rb3, (float*)d_out);
}